// Round 2
// baseline (4837.435 us; speedup 1.0000x reference)
//
#include <hip/hip_runtime.h>
#include <math.h>

// ---------------------------------------------------------------------------
// DCN_89859305767621
// Round 2: fix replay divergence (suspected d_ws overflow: 223MB -> 121MB).
//  - compact x_dc [N,44], in-place GCN buffers (302N floats total)
//  - fusion tail (dnn+cross+pred) in ONE kernel, intermediates in LDS
// ---------------------------------------------------------------------------

__global__ __launch_bounds__(256) void embed_kernel(
    const int* __restrict__ disc, const float* __restrict__ cont,
    const float* __restrict__ Wc, const float* __restrict__ bc,
    float* __restrict__ xdc, int N)
{
    __shared__ float Ws[120];
    __shared__ float bs[4];
    if (threadIdx.x < 120) Ws[threadIdx.x] = Wc[threadIdx.x];
    if (threadIdx.x < 4)   bs[threadIdx.x] = bc[threadIdx.x];
    __syncthreads();
    int row = blockIdx.x * 256 + threadIdx.x;
    if (row >= N) return;
    const int* dr = disc + (size_t)row * 38;
    float* xr = xdc + (size_t)row * 44;
    int best = dr[0], idx = 0;
    #pragma unroll
    for (int j = 1; j < 7; ++j) { int v = dr[j]; if (v > best) { best = v; idx = j; } }
    xr[0] = (float)idx;
    #pragma unroll
    for (int j = 7; j < 38; ++j) xr[j - 6] = (float)dr[j];
    const float* cr = cont + (size_t)row * 90;
    #pragma unroll
    for (int t = 0; t < 3; ++t) {
        float s0 = bs[0], s1 = bs[1], s2 = bs[2], s3 = bs[3];
        for (int j = 0; j < 30; ++j) {
            float v = cr[t * 30 + j];
            s0 += v * Ws[j * 4 + 0];
            s1 += v * Ws[j * 4 + 1];
            s2 += v * Ws[j * 4 + 2];
            s3 += v * Ws[j * 4 + 3];
        }
        xr[32 + t * 4 + 0] = s0;
        xr[32 + t * 4 + 1] = s1;
        xr[32 + t * 4 + 2] = s2;
        xr[32 + t * 4 + 3] = s3;
    }
}

// C[N,128] = act(A[N,K] @ W[K,128] + bias). In-place (C==A) is safe: each
// block stages only its own TM rows into LDS before writing them back.
template<int K, int TM, int ACT>
__global__ __launch_bounds__(256) void fc_kernel(
    const float* __restrict__ A, int lda,
    const float* __restrict__ W, const float* __restrict__ bias,
    float* __restrict__ C, int ldc, int N)
{
    constexpr int NJ = 2;          // 128 cols = lane + 64*j
    constexpr int KC = 32;
    constexpr int RB = TM / 4;
    __shared__ float Alds[TM][K];
    __shared__ float Wlds[KC][128];
    const int tid = threadIdx.x;
    const int lane = tid & 63;
    const int wv = tid >> 6;
    const int row0 = blockIdx.x * TM;

    for (int idx = tid; idx < TM * K; idx += 256) {
        int r = idx / K, k = idx - r * K;
        int row = row0 + r;
        Alds[r][k] = (row < N) ? A[(size_t)row * lda + k] : 0.f;
    }

    float acc[RB][NJ];
    #pragma unroll
    for (int r = 0; r < RB; ++r)
        #pragma unroll
        for (int j = 0; j < NJ; ++j)
            acc[r][j] = (bias != nullptr) ? bias[lane + 64 * j] : 0.f;

    for (int k0 = 0; k0 < K; k0 += KC) {
        const int kc = (K - k0 < KC) ? (K - k0) : KC;
        __syncthreads();
        for (int idx = tid; idx < kc * 128; idx += 256) {
            int kk = idx >> 7, c = idx & 127;
            Wlds[kk][c] = W[(size_t)(k0 + kk) * 128 + c];
        }
        __syncthreads();
        for (int kk = 0; kk < kc; ++kk) {
            float w0 = Wlds[kk][lane];
            float w1 = Wlds[kk][lane + 64];
            #pragma unroll
            for (int r = 0; r < RB; ++r) {
                float a = Alds[wv * RB + r][k0 + kk];
                acc[r][0] += a * w0;
                acc[r][1] += a * w1;
            }
        }
    }
    __syncthreads();   // all reads of A-tile done before (possible) in-place write

    #pragma unroll
    for (int r = 0; r < RB; ++r) {
        int row = row0 + wv * RB + r;
        if (row >= N) continue;
        #pragma unroll
        for (int j = 0; j < NJ; ++j) {
            float v = acc[r][j];
            if (ACT == 1) v = v > 0.f ? v : 0.01f * v;
            C[(size_t)row * ldc + lane + 64 * j] = v;
        }
    }
}

__global__ __launch_bounds__(256) void deg_init_kernel(float* __restrict__ deg, int N)
{
    int i = blockIdx.x * 256 + threadIdx.x;
    if (i < N) deg[i] = 1.0f;
}

__global__ __launch_bounds__(256) void deg_edge_kernel(const int* __restrict__ dst,
                                                       float* __restrict__ deg, int E)
{
    int i = blockIdx.x * 256 + threadIdx.x;
    if (i < E) atomicAdd(&deg[dst[i]], 1.0f);
}

__global__ __launch_bounds__(256) void dis_kernel(const float* __restrict__ deg,
                                                  float* __restrict__ dis, int N)
{
    int i = blockIdx.x * 256 + threadIdx.x;
    if (i < N) dis[i] = rsqrtf(deg[i]);
}

// one wave per edge; lane handles 2 of 128 feature dims
__global__ __launch_bounds__(256) void scatter_kernel(
    const float* __restrict__ xw, const int* __restrict__ src,
    const int* __restrict__ dst, const float* __restrict__ dis,
    float* __restrict__ agg, int E)
{
    int wid = (int)(((size_t)blockIdx.x * 256 + threadIdx.x) >> 6);
    int lane = threadIdx.x & 63;
    int nw = (gridDim.x * 256) >> 6;
    for (int e = wid; e < E; e += nw) {
        int s = src[e], d = dst[e];
        float coeff = dis[s] * dis[d];
        float2 v = ((const float2*)(xw + (size_t)s * 128))[lane];
        atomicAdd(&agg[(size_t)d * 128 + 2 * lane],     v.x * coeff);
        atomicAdd(&agg[(size_t)d * 128 + 2 * lane + 1], v.y * coeff);
    }
}

// xg <- leaky(agg + xg/deg + b)  (elementwise, in place over xg)
__global__ __launch_bounds__(256) void gcn_combine_kernel(
    float* __restrict__ xg, const float* __restrict__ agg,
    const float* __restrict__ dis, const float* __restrict__ b, int N)
{
    size_t idx = (size_t)blockIdx.x * 256 + threadIdx.x;
    if (idx >= (size_t)N * 128) return;
    int row = (int)(idx >> 7);
    int d = (int)(idx & 127);
    float dd = dis[row];
    float v = agg[idx] + xg[idx] * dd * dd + b[d];
    xg[idx] = v > 0.f ? v : 0.01f * v;
}

// Fusion tail: x=[xdc|xg] -> dnn1 -> dnn2 -> cross x2 -> pred1 -> pred2 -> sigmoid
// TM=16 rows per block, 256 threads (4 waves x 4 rows), all intermediates in LDS.
__global__ __launch_bounds__(256) void fusion_kernel(
    const float* __restrict__ xdc, const float* __restrict__ xg,
    const float* __restrict__ W1, const float* __restrict__ b1,
    const float* __restrict__ W2, const float* __restrict__ b2,
    const float* __restrict__ crossw, const float* __restrict__ crossb,
    const float* __restrict__ PW1, const float* __restrict__ Pb1,
    const float* __restrict__ PW2, const float* __restrict__ Pb2,
    float* __restrict__ out, int N)
{
    constexpr int TM = 16, RB = 4, NJ = 3, D = 172, KC = 32, NC = 192;
    __shared__ float Xs[TM][D];   // x (x0 for cross)
    __shared__ float Ts[TM][D];   // t1, then xdeep (in place)
    __shared__ float Ls[TM][D];   // xl
    __shared__ float Wlds[KC][NC];
    const int tid = threadIdx.x, lane = tid & 63, wv = tid >> 6;
    const int row0 = blockIdx.x * TM;

    // ---- stage x rows
    for (int idx = tid; idx < TM * 44; idx += 256) {
        int r = idx / 44, k = idx - r * 44;
        int row = row0 + r;
        Xs[r][k] = (row < N) ? xdc[(size_t)row * 44 + k] : 0.f;
    }
    for (int idx = tid; idx < TM * 128; idx += 256) {
        int r = idx >> 7, k = idx & 127;
        int row = row0 + r;
        Xs[r][44 + k] = (row < N) ? xg[(size_t)row * 128 + k] : 0.f;
    }
    __syncthreads();

    int cc[NJ];
    #pragma unroll
    for (int j = 0; j < NJ; ++j) cc[j] = lane + 64 * j;

    float acc[RB][NJ];

    // ---- chunked GEMM from LDS rows (S1 for k<172, S2 for k>=172)
    auto gemm = [&](const float (*S1)[D], const float (*S2)[D], int KT,
                    const float* __restrict__ W, const float* __restrict__ bias) {
        #pragma unroll
        for (int r = 0; r < RB; ++r)
            #pragma unroll
            for (int j = 0; j < NJ; ++j)
                acc[r][j] = (cc[j] < D) ? bias[cc[j]] : 0.f;
        for (int k0 = 0; k0 < KT; k0 += KC) {
            const int kc = (KT - k0 < KC) ? (KT - k0) : KC;
            __syncthreads();
            for (int idx = tid; idx < kc * NC; idx += 256) {
                int kk = idx / NC, c = idx - kk * NC;
                Wlds[kk][c] = (c < D) ? W[(size_t)(k0 + kk) * D + c] : 0.f;
            }
            __syncthreads();
            for (int kk = 0; kk < kc; ++kk) {
                const int k = k0 + kk;
                float wvv[NJ];
                #pragma unroll
                for (int j = 0; j < NJ; ++j) wvv[j] = Wlds[kk][cc[j]];
                #pragma unroll
                for (int r = 0; r < RB; ++r) {
                    const int rw = wv * RB + r;
                    float a = (k < D) ? S1[rw][k] : S2[rw][k - D];
                    #pragma unroll
                    for (int j = 0; j < NJ; ++j) acc[r][j] += a * wvv[j];
                }
            }
        }
    };

    // ---- dnn1: t1 = leaky(x @ W1 + b1)
    gemm(Xs, Xs, D, W1, b1);
    #pragma unroll
    for (int r = 0; r < RB; ++r) {
        const int rw = wv * RB + r;
        #pragma unroll
        for (int j = 0; j < NJ; ++j)
            if (cc[j] < D) {
                float v = acc[r][j];
                Ts[rw][cc[j]] = v > 0.f ? v : 0.01f * v;
            }
    }
    // ---- dnn2: xdeep = leaky(t1 @ W2 + b2)  (in place over Ts)
    gemm(Ts, Ts, D, W2, b2);
    __syncthreads();
    #pragma unroll
    for (int r = 0; r < RB; ++r) {
        const int rw = wv * RB + r;
        #pragma unroll
        for (int j = 0; j < NJ; ++j)
            if (cc[j] < D) {
                float v = acc[r][j];
                Ts[rw][cc[j]] = v > 0.f ? v : 0.01f * v;
            }
    }

    // ---- cross: xl = x; 2 layers of xl = x0*(xl.w) + b + xl (wave-local rows)
    #pragma unroll
    for (int r = 0; r < RB; ++r) {
        const int rw = wv * RB + r;
        Ls[rw][lane] = Xs[rw][lane];
        Ls[rw][lane + 64] = Xs[rw][lane + 64];
        if (lane < D - 128) Ls[rw][lane + 128] = Xs[rw][lane + 128];
    }
    for (int l = 0; l < 2; ++l) {
        const float* w = crossw + l * D;
        const float* b = crossb + l * D;
        float w0 = w[lane], w1 = w[lane + 64];
        float w2 = (lane < D - 128) ? w[lane + 128] : 0.f;
        #pragma unroll
        for (int r = 0; r < RB; ++r) {
            const int rw = wv * RB + r;
            float v0 = Ls[rw][lane], v1 = Ls[rw][lane + 64];
            float v2 = (lane < D - 128) ? Ls[rw][lane + 128] : 0.f;
            float p = v0 * w0 + v1 * w1 + v2 * w2;
            #pragma unroll
            for (int off = 32; off > 0; off >>= 1) p += __shfl_xor(p, off, 64);
            Ls[rw][lane]      = Xs[rw][lane]      * p + b[lane]      + v0;
            Ls[rw][lane + 64] = Xs[rw][lane + 64] * p + b[lane + 64] + v1;
            if (lane < D - 128)
                Ls[rw][lane + 128] = Xs[rw][lane + 128] * p + b[lane + 128] + v2;
        }
    }

    // ---- pred1: h = [xdeep | xl], p1 = leaky(h @ PW1 + Pb1) (kept in regs)
    gemm(Ts, Ls, 2 * D, PW1, Pb1);

    // ---- pred2 + sigmoid
    float w2v[NJ];
    #pragma unroll
    for (int j = 0; j < NJ; ++j) w2v[j] = (cc[j] < D) ? PW2[cc[j]] : 0.f;
    #pragma unroll
    for (int r = 0; r < RB; ++r) {
        float s = 0.f;
        #pragma unroll
        for (int j = 0; j < NJ; ++j) {
            float v = acc[r][j];
            v = v > 0.f ? v : 0.01f * v;
            s += v * w2v[j];
        }
        #pragma unroll
        for (int off = 32; off > 0; off >>= 1) s += __shfl_xor(s, off, 64);
        const int row = row0 + wv * RB + r;
        if (lane == 0 && row < N)
            out[row] = 1.f / (1.f + expf(-(s + Pb2[0])));
    }
}

extern "C" void kernel_launch(void* const* d_in, const int* in_sizes, int n_in,
                              void* d_out, int out_size, void* d_ws, size_t ws_size,
                              hipStream_t stream)
{
    const int*   disc    = (const int*)d_in[0];
    const float* cont    = (const float*)d_in[1];
    const int*   eidx    = (const int*)d_in[2];
    const float* emb_W   = (const float*)d_in[5];
    const float* emb_b   = (const float*)d_in[6];
    const float* g0_W    = (const float*)d_in[7];
    const float* g0_b    = (const float*)d_in[8];
    const float* gcn1_W  = (const float*)d_in[9];
    const float* gcn1_b  = (const float*)d_in[10];
    const float* gcn2_W  = (const float*)d_in[11];
    const float* gcn2_b  = (const float*)d_in[12];
    const float* dnn_W1  = (const float*)d_in[13];
    const float* dnn_b1  = (const float*)d_in[14];
    const float* dnn_W2  = (const float*)d_in[15];
    const float* dnn_b2  = (const float*)d_in[16];
    const float* cross_w = (const float*)d_in[17];
    const float* cross_b = (const float*)d_in[18];
    const float* pred_W1 = (const float*)d_in[19];
    const float* pred_b1 = (const float*)d_in[20];
    const float* pred_W2 = (const float*)d_in[21];
    const float* pred_b2 = (const float*)d_in[22];

    const int N = in_sizes[0] / 38;
    const int E = in_sizes[2] / 2;
    const int* src = eidx;
    const int* dst = eidx + E;

    // workspace: 302N floats total (~121 MB @ N=1e5)
    float* ws   = (float*)d_ws;
    float* xdc  = ws;                       // [N,44]
    float* xg   = ws + (size_t)N * 44;      // [N,128] x_g / xw (in place)
    float* agg  = ws + (size_t)N * 172;     // [N,128]
    float* deg  = ws + (size_t)N * 300;     // [N]
    float* dis  = ws + (size_t)N * 301;     // [N]

    auto cdiv = [](int a, int b) { return (a + b - 1) / b; };

    embed_kernel<<<cdiv(N, 256), 256, 0, stream>>>(disc, cont, emb_W, emb_b, xdc, N);

    deg_init_kernel<<<cdiv(N, 256), 256, 0, stream>>>(deg, N);
    deg_edge_kernel<<<cdiv(E, 256), 256, 0, stream>>>(dst, deg, E);
    dis_kernel<<<cdiv(N, 256), 256, 0, stream>>>(deg, dis, N);

    // g0: [N,44]@[44,128] -> xg
    fc_kernel<44, 32, 1><<<cdiv(N, 32), 256, 0, stream>>>(
        xdc, 44, g0_W, g0_b, xg, 128, N);

    // GCN layer 1 (in place over xg)
    fc_kernel<128, 32, 0><<<cdiv(N, 32), 256, 0, stream>>>(
        xg, 128, gcn1_W, nullptr, xg, 128, N);
    hipMemsetAsync(agg, 0, (size_t)N * 128 * sizeof(float), stream);
    scatter_kernel<<<8192, 256, 0, stream>>>(xg, src, dst, dis, agg, E);
    gcn_combine_kernel<<<cdiv(N * 128, 256), 256, 0, stream>>>(xg, agg, dis, gcn1_b, N);

    // GCN layer 2
    fc_kernel<128, 32, 0><<<cdiv(N, 32), 256, 0, stream>>>(
        xg, 128, gcn2_W, nullptr, xg, 128, N);
    hipMemsetAsync(agg, 0, (size_t)N * 128 * sizeof(float), stream);
    scatter_kernel<<<8192, 256, 0, stream>>>(xg, src, dst, dis, agg, E);
    gcn_combine_kernel<<<cdiv(N * 128, 256), 256, 0, stream>>>(xg, agg, dis, gcn2_b, N);

    // fusion tail -> d_out
    fusion_kernel<<<cdiv(N, 16), 256, 0, stream>>>(
        xdc, xg, dnn_W1, dnn_b1, dnn_W2, dnn_b2, cross_w, cross_b,
        pred_W1, pred_b1, pred_W2, pred_b2, (float*)d_out, N);
}

// Round 3
// 2021.018 us; speedup vs baseline: 2.3936x; 2.3936x over previous
//
#include <hip/hip_runtime.h>
#include <math.h>

// ---------------------------------------------------------------------------
// DCN_89859305767621  Round 3:
//  - CSR (count/scan/fill) + gather-side GCN aggregation, no f32 atomics
//  - fused self-loop+bias+leaky into aggregation
//  - embed fused into g0 staging and fusion staging (no xdc buffer)
//  - fusion LDS 57.8->45.3 KB (3 blocks/CU), float4 staging in fc kernels
// ---------------------------------------------------------------------------

__device__ __forceinline__ float leakyf(float v) { return v > 0.f ? v : 0.01f * v; }

// Compute x_d|x_c (44 features) for TM rows into LDS (stride ldx).
__device__ __forceinline__ void stage_embed(
    const int* __restrict__ disc, const float* __restrict__ cont,
    const float* __restrict__ Wc, const float* __restrict__ bc,
    float* __restrict__ Xs, int ldx, int row0, int TM, int N, int tid)
{
    for (int idx = tid; idx < TM * 38; idx += 256) {
        int r = idx / 38, j = idx - r * 38;
        int row = row0 + r;
        if (j == 0) {
            float o = 0.f;
            if (row < N) {
                const int* dr = disc + (size_t)row * 38;
                int best = dr[0], bi = 0;
                #pragma unroll
                for (int q = 1; q < 7; ++q) { int v = dr[q]; if (v > best) { best = v; bi = q; } }
                o = (float)bi;
            }
            Xs[r * ldx] = o;
        } else if (j >= 7) {
            Xs[r * ldx + j - 6] = (row < N) ? (float)disc[(size_t)row * 38 + j] : 0.f;
        }
    }
    for (int idx = tid; idx < TM * 12; idx += 256) {
        int r = idx / 12, q = idx - r * 12;
        int t = q >> 2, ch = q & 3;
        int row = row0 + r;
        float s = 0.f;
        if (row < N) {
            s = bc[ch];
            const float* cr = cont + (size_t)row * 90 + t * 30;
            #pragma unroll
            for (int j = 0; j < 30; ++j) s += cr[j] * Wc[j * 4 + ch];
        }
        Xs[r * ldx + 32 + t * 4 + ch] = s;
    }
}

// ---------------- CSR build ----------------
__global__ __launch_bounds__(256) void cnt_edge_kernel(const int* __restrict__ dst,
                                                       int* __restrict__ cnt, int E)
{
    int i = blockIdx.x * 256 + threadIdx.x;
    if (i < E) atomicAdd(&cnt[dst[i]], 1);
}

__global__ __launch_bounds__(256) void scan1_kernel(const int* __restrict__ cnt,
                                                    int* __restrict__ incl,
                                                    int* __restrict__ bsum, int N)
{
    __shared__ int s[256];
    int tid = threadIdx.x;
    int i = blockIdx.x * 256 + tid;
    s[tid] = (i < N) ? cnt[i] : 0;
    __syncthreads();
    #pragma unroll
    for (int off = 1; off < 256; off <<= 1) {
        int t = (tid >= off) ? s[tid - off] : 0;
        __syncthreads();
        s[tid] += t;
        __syncthreads();
    }
    if (i < N) incl[i] = s[tid];
    if (tid == 255) bsum[blockIdx.x] = s[255];
}

__global__ void scan2_kernel(int* __restrict__ bsum, int nb)   // 1 block, 64 threads
{
    int lane = threadIdx.x & 63;
    int run = 0;
    for (int base = 0; base < nb; base += 64) {
        int i = base + lane;
        int orig = (i < nb) ? bsum[i] : 0;
        int v = orig;
        #pragma unroll
        for (int off = 1; off < 64; off <<= 1) {
            int t = __shfl_up(v, off, 64);
            if (lane >= off) v += t;
        }
        if (i < nb) bsum[i] = run + v - orig;       // exclusive
        run += __shfl(v, 63, 64);
    }
}

__global__ __launch_bounds__(256) void scan3_kernel(const int* __restrict__ incl,
                                                    const int* __restrict__ cnt,
                                                    const int* __restrict__ bsum,
                                                    int* __restrict__ row_ptr,
                                                    int* __restrict__ cursor, int N)
{
    int i = blockIdx.x * 256 + threadIdx.x;
    if (i < N) {
        int v = incl[i] - cnt[i] + bsum[i >> 8];
        row_ptr[i] = v;
        cursor[i] = v;
    }
}

__global__ __launch_bounds__(256) void fill_kernel(const int* __restrict__ src,
                                                   const int* __restrict__ dst,
                                                   int* __restrict__ cursor,
                                                   int* __restrict__ colE, int E)
{
    int e = blockIdx.x * 256 + threadIdx.x;
    if (e < E) {
        int p = atomicAdd(&cursor[dst[e]], 1);
        colE[p] = src[e];
    }
}

__global__ __launch_bounds__(256) void dis_kernel(const int* __restrict__ cnt,
                                                  float* __restrict__ dis, int N)
{
    int i = blockIdx.x * 256 + threadIdx.x;
    if (i < N) dis[i] = rsqrtf((float)cnt[i] + 1.0f);
}

// ---------------- g0: embed -> [N,44] @ [44,128] + b, leaky ----------------
__global__ __launch_bounds__(256) void g0_kernel(
    const int* __restrict__ disc, const float* __restrict__ cont,
    const float* __restrict__ Wc, const float* __restrict__ bc,
    const float* __restrict__ W, const float* __restrict__ bias,
    float* __restrict__ C, int N)
{
    constexpr int TM = 32, K = 44, RB = 8;
    __shared__ float Alds[TM][K];
    __shared__ float Wlds[K][128];
    const int tid = threadIdx.x, lane = tid & 63, wv = tid >> 6;
    const int row0 = blockIdx.x * TM;

    stage_embed(disc, cont, Wc, bc, &Alds[0][0], K, row0, TM, N, tid);
    for (int idx = tid; idx < K * 32; idx += 256) {
        int k = idx >> 5, c4 = idx & 31;
        ((float4*)&Wlds[k][0])[c4] = ((const float4*)W)[idx];
    }
    __syncthreads();

    float acc[RB][2];
    float b0 = bias[lane], b1 = bias[lane + 64];
    #pragma unroll
    for (int r = 0; r < RB; ++r) { acc[r][0] = b0; acc[r][1] = b1; }

    for (int k = 0; k < K; ++k) {
        float w0 = Wlds[k][lane], w1 = Wlds[k][lane + 64];
        #pragma unroll
        for (int r = 0; r < RB; ++r) {
            float a = Alds[wv * RB + r][k];
            acc[r][0] += a * w0;
            acc[r][1] += a * w1;
        }
    }
    #pragma unroll
    for (int r = 0; r < RB; ++r) {
        int row = row0 + wv * RB + r;
        if (row < N) {
            C[(size_t)row * 128 + lane]      = leakyf(acc[r][0]);
            C[(size_t)row * 128 + lane + 64] = leakyf(acc[r][1]);
        }
    }
}

// ---------------- fc: [N,128] @ [128,128] (no bias/act) ----------------
__global__ __launch_bounds__(256) void fc128_kernel(
    const float* __restrict__ A, const float* __restrict__ W,
    float* __restrict__ C, int N)
{
    constexpr int TM = 32, RB = 8, KC = 32;
    __shared__ float Alds[TM][128];
    __shared__ float Wlds[KC][128];
    const int tid = threadIdx.x, lane = tid & 63, wv = tid >> 6;
    const int row0 = blockIdx.x * TM;

    for (int idx = tid; idx < TM * 32; idx += 256) {
        int r = idx >> 5, c4 = idx & 31;
        int row = row0 + r;
        float4 v = make_float4(0.f, 0.f, 0.f, 0.f);
        if (row < N) v = ((const float4*)(A + (size_t)row * 128))[c4];
        ((float4*)&Alds[r][0])[c4] = v;
    }

    float acc[RB][2];
    #pragma unroll
    for (int r = 0; r < RB; ++r) { acc[r][0] = 0.f; acc[r][1] = 0.f; }

    for (int k0 = 0; k0 < 128; k0 += KC) {
        __syncthreads();
        for (int idx = tid; idx < KC * 32; idx += 256) {
            int k = idx >> 5, c4 = idx & 31;
            ((float4*)&Wlds[k][0])[c4] = ((const float4*)W)[(size_t)(k0 + k) * 32 + c4];
        }
        __syncthreads();
        #pragma unroll 4
        for (int kk = 0; kk < KC; ++kk) {
            float w0 = Wlds[kk][lane], w1 = Wlds[kk][lane + 64];
            #pragma unroll
            for (int r = 0; r < RB; ++r) {
                float a = Alds[wv * RB + r][k0 + kk];
                acc[r][0] += a * w0;
                acc[r][1] += a * w1;
            }
        }
    }
    #pragma unroll
    for (int r = 0; r < RB; ++r) {
        int row = row0 + wv * RB + r;
        if (row < N) {
            C[(size_t)row * 128 + lane]      = acc[r][0];
            C[(size_t)row * 128 + lane + 64] = acc[r][1];
        }
    }
}

// ---------------- GCN aggregation: gather over CSR, fused combine ----------
__global__ __launch_bounds__(256) void agg_kernel(
    const float* __restrict__ B, const int* __restrict__ colE,
    const int* __restrict__ row_ptr, const int* __restrict__ cnt,
    const float* __restrict__ dis, const float* __restrict__ bias,
    float* __restrict__ A, int N)
{
    int gw = (int)(((size_t)blockIdx.x * 256 + threadIdx.x) >> 6);
    int lane = threadIdx.x & 63;
    if (gw >= N) return;
    const float2* B2 = (const float2*)B;
    float dn = dis[gw];
    int st = row_ptr[gw], c = cnt[gw];
    float ax = 0.f, ay = 0.f;
    for (int i = 0; i < c; ++i) {
        int s = colE[st + i];
        float cf = dis[s] * dn;
        float2 v = B2[(size_t)s * 64 + lane];
        ax += v.x * cf;
        ay += v.y * cf;
    }
    float2 sv = B2[(size_t)gw * 64 + lane];
    float d2 = dn * dn;
    ax += sv.x * d2;
    ay += sv.y * d2;
    float2 bb = ((const float2*)bias)[lane];
    float2 o;
    o.x = leakyf(ax + bb.x);
    o.y = leakyf(ay + bb.y);
    ((float2*)A)[(size_t)gw * 64 + lane] = o;
}

// ---------------- fusion tail ----------------
__global__ __launch_bounds__(256) void fusion_kernel(
    const int* __restrict__ disc, const float* __restrict__ cont,
    const float* __restrict__ Wc, const float* __restrict__ bc,
    const float* __restrict__ xg,
    const float* __restrict__ W1, const float* __restrict__ b1,
    const float* __restrict__ W2, const float* __restrict__ b2,
    const float* __restrict__ crossw, const float* __restrict__ crossb,
    const float* __restrict__ PW1, const float* __restrict__ Pb1,
    const float* __restrict__ PW2, const float* __restrict__ Pb2,
    float* __restrict__ out, int N)
{
    constexpr int TM = 16, RB = 4, NJ = 3, D = 172, KC = 16, NC = 192;
    __shared__ float Xs[TM][D];
    __shared__ float Ts[TM][D];
    __shared__ float Ls[TM][D];
    __shared__ float Wlds[KC][NC];
    const int tid = threadIdx.x, lane = tid & 63, wv = tid >> 6;
    const int row0 = blockIdx.x * TM;

    stage_embed(disc, cont, Wc, bc, &Xs[0][0], D, row0, TM, N, tid);
    for (int idx = tid; idx < TM * 128; idx += 256) {
        int r = idx >> 7, k = idx & 127;
        int row = row0 + r;
        Xs[r][44 + k] = (row < N) ? xg[(size_t)row * 128 + k] : 0.f;
    }
    __syncthreads();

    int cc[NJ];
    #pragma unroll
    for (int j = 0; j < NJ; ++j) cc[j] = lane + 64 * j;

    float acc[RB][NJ];

    auto gemm = [&](const float (*S1)[D], const float (*S2)[D], int KT,
                    const float* __restrict__ W, const float* __restrict__ bias) {
        #pragma unroll
        for (int r = 0; r < RB; ++r)
            #pragma unroll
            for (int j = 0; j < NJ; ++j)
                acc[r][j] = (cc[j] < D) ? bias[cc[j]] : 0.f;
        for (int k0 = 0; k0 < KT; k0 += KC) {
            const int kc = (KT - k0 < KC) ? (KT - k0) : KC;
            __syncthreads();
            for (int idx = tid; idx < kc * NC; idx += 256) {
                int kk = idx / NC, c = idx - kk * NC;
                Wlds[kk][c] = (c < D) ? W[(size_t)(k0 + kk) * D + c] : 0.f;
            }
            __syncthreads();
            for (int kk = 0; kk < kc; ++kk) {
                const int k = k0 + kk;
                float wvv[NJ];
                #pragma unroll
                for (int j = 0; j < NJ; ++j) wvv[j] = Wlds[kk][cc[j]];
                #pragma unroll
                for (int r = 0; r < RB; ++r) {
                    const int rw = wv * RB + r;
                    float a = (k < D) ? S1[rw][k] : S2[rw][k - D];
                    #pragma unroll
                    for (int j = 0; j < NJ; ++j) acc[r][j] += a * wvv[j];
                }
            }
        }
    };

    // dnn1
    gemm(Xs, Xs, D, W1, b1);
    #pragma unroll
    for (int r = 0; r < RB; ++r) {
        const int rw = wv * RB + r;
        #pragma unroll
        for (int j = 0; j < NJ; ++j)
            if (cc[j] < D) Ts[rw][cc[j]] = leakyf(acc[r][j]);
    }
    // dnn2 (in place over Ts)
    gemm(Ts, Ts, D, W2, b2);
    __syncthreads();
    #pragma unroll
    for (int r = 0; r < RB; ++r) {
        const int rw = wv * RB + r;
        #pragma unroll
        for (int j = 0; j < NJ; ++j)
            if (cc[j] < D) Ts[rw][cc[j]] = leakyf(acc[r][j]);
    }

    // cross x2
    #pragma unroll
    for (int r = 0; r < RB; ++r) {
        const int rw = wv * RB + r;
        Ls[rw][lane] = Xs[rw][lane];
        Ls[rw][lane + 64] = Xs[rw][lane + 64];
        if (lane < D - 128) Ls[rw][lane + 128] = Xs[rw][lane + 128];
    }
    for (int l = 0; l < 2; ++l) {
        const float* w = crossw + l * D;
        const float* b = crossb + l * D;
        float w0 = w[lane], w1 = w[lane + 64];
        float w2 = (lane < D - 128) ? w[lane + 128] : 0.f;
        #pragma unroll
        for (int r = 0; r < RB; ++r) {
            const int rw = wv * RB + r;
            float v0 = Ls[rw][lane], v1 = Ls[rw][lane + 64];
            float v2 = (lane < D - 128) ? Ls[rw][lane + 128] : 0.f;
            float p = v0 * w0 + v1 * w1 + v2 * w2;
            #pragma unroll
            for (int off = 32; off > 0; off >>= 1) p += __shfl_xor(p, off, 64);
            Ls[rw][lane]      = Xs[rw][lane]      * p + b[lane]      + v0;
            Ls[rw][lane + 64] = Xs[rw][lane + 64] * p + b[lane + 64] + v1;
            if (lane < D - 128)
                Ls[rw][lane + 128] = Xs[rw][lane + 128] * p + b[lane + 128] + v2;
        }
    }

    // pred1 (regs) -> pred2 -> sigmoid
    gemm(Ts, Ls, 2 * D, PW1, Pb1);

    float w2v[NJ];
    #pragma unroll
    for (int j = 0; j < NJ; ++j) w2v[j] = (cc[j] < D) ? PW2[cc[j]] : 0.f;
    #pragma unroll
    for (int r = 0; r < RB; ++r) {
        float s = 0.f;
        #pragma unroll
        for (int j = 0; j < NJ; ++j) {
            float v = acc[r][j];
            v = leakyf(v);
            s += v * w2v[j];
        }
        #pragma unroll
        for (int off = 32; off > 0; off >>= 1) s += __shfl_xor(s, off, 64);
        const int row = row0 + wv * RB + r;
        if (lane == 0 && row < N)
            out[row] = 1.f / (1.f + expf(-(s + Pb2[0])));
    }
}

extern "C" void kernel_launch(void* const* d_in, const int* in_sizes, int n_in,
                              void* d_out, int out_size, void* d_ws, size_t ws_size,
                              hipStream_t stream)
{
    const int*   disc    = (const int*)d_in[0];
    const float* cont    = (const float*)d_in[1];
    const int*   eidx    = (const int*)d_in[2];
    const float* emb_W   = (const float*)d_in[5];
    const float* emb_b   = (const float*)d_in[6];
    const float* g0_W    = (const float*)d_in[7];
    const float* g0_b    = (const float*)d_in[8];
    const float* gcn1_W  = (const float*)d_in[9];
    const float* gcn1_b  = (const float*)d_in[10];
    const float* gcn2_W  = (const float*)d_in[11];
    const float* gcn2_b  = (const float*)d_in[12];
    const float* dnn_W1  = (const float*)d_in[13];
    const float* dnn_b1  = (const float*)d_in[14];
    const float* dnn_W2  = (const float*)d_in[15];
    const float* dnn_b2  = (const float*)d_in[16];
    const float* cross_w = (const float*)d_in[17];
    const float* cross_b = (const float*)d_in[18];
    const float* pred_W1 = (const float*)d_in[19];
    const float* pred_b1 = (const float*)d_in[20];
    const float* pred_W2 = (const float*)d_in[21];
    const float* pred_b2 = (const float*)d_in[22];

    const int N = in_sizes[0] / 38;
    const int E = in_sizes[2] / 2;
    const int* src = eidx;
    const int* dst = eidx + E;

    // workspace (~111 MB @ N=1e5, E=1.6e6)
    float* ws   = (float*)d_ws;
    float* A    = ws;                        // [N,128]
    float* B    = ws + (size_t)N * 128;      // [N,128]
    float* dis  = ws + (size_t)N * 256;      // [N]
    int* ib     = (int*)(ws + (size_t)N * 257);
    int* cnt    = ib;                        // [N]
    int* incl   = ib + (size_t)N;            // [N]
    int* rowp   = ib + (size_t)N * 2;        // [N]
    int* cursor = ib + (size_t)N * 3;        // [N]
    int* bsum   = ib + (size_t)N * 4;        // [512]
    int* colE   = ib + (size_t)N * 4 + 512;  // [E]

    auto cdiv = [](int a, int b) { return (a + b - 1) / b; };
    const int nb = cdiv(N, 256);

    // CSR build
    hipMemsetAsync(cnt, 0, (size_t)N * sizeof(int), stream);
    cnt_edge_kernel<<<cdiv(E, 256), 256, 0, stream>>>(dst, cnt, E);
    scan1_kernel<<<nb, 256, 0, stream>>>(cnt, incl, bsum, N);
    scan2_kernel<<<1, 64, 0, stream>>>(bsum, nb);
    scan3_kernel<<<nb, 256, 0, stream>>>(incl, cnt, bsum, rowp, cursor, N);
    fill_kernel<<<cdiv(E, 256), 256, 0, stream>>>(src, dst, cursor, colE, E);
    dis_kernel<<<cdiv(N, 256), 256, 0, stream>>>(cnt, dis, N);

    // g0 (embed fused) -> A
    g0_kernel<<<cdiv(N, 32), 256, 0, stream>>>(disc, cont, emb_W, emb_b, g0_W, g0_b, A, N);

    // GCN layer 1: A @ W -> B ; gather(B) -> A
    fc128_kernel<<<cdiv(N, 32), 256, 0, stream>>>(A, gcn1_W, B, N);
    agg_kernel<<<cdiv(N, 4), 256, 0, stream>>>(B, colE, rowp, cnt, dis, gcn1_b, A, N);

    // GCN layer 2
    fc128_kernel<<<cdiv(N, 32), 256, 0, stream>>>(A, gcn2_W, B, N);
    agg_kernel<<<cdiv(N, 4), 256, 0, stream>>>(B, colE, rowp, cnt, dis, gcn2_b, A, N);

    // fusion tail -> d_out
    fusion_kernel<<<cdiv(N, 16), 256, 0, stream>>>(
        disc, cont, emb_W, emb_b, A,
        dnn_W1, dnn_b1, dnn_W2, dnn_b2, cross_w, cross_b,
        pred_W1, pred_b1, pred_W2, pred_b2, (float*)d_out, N);
}

// Round 5
// 979.902 us; speedup vs baseline: 4.9367x; 2.0625x over previous
//
#include <hip/hip_runtime.h>
#include <math.h>

// ---------------------------------------------------------------------------
// DCN_89859305767621  Round 5:
//  - fix replay divergence: footprint 146.7 MB -> ~111 MB (proven-safe level)
//  - algebraic cross (xl = alpha*x0 + const) -> xl never materialized
//  - fused tail: A(dnn1+dnn2+pred1a) -> partA bf16; B(cross-alpha+pred1b+sigmoid)
//  - split-bf16 packed-u32 storage for xg and all weights; MFMA 16x16x32
// ---------------------------------------------------------------------------

typedef __attribute__((ext_vector_type(8))) short bf16x8;
typedef __attribute__((ext_vector_type(4))) float f32x4;

__device__ __forceinline__ float leakyf(float v) { return v > 0.f ? v : 0.01f * v; }

__device__ __forceinline__ ushort rnd_bf16(float x) {
    unsigned u = __builtin_bit_cast(unsigned, x);
    return (ushort)((u + 0x8000u) >> 16);
}
__device__ __forceinline__ unsigned pack_split(float x) {
    ushort h = rnd_bf16(x);
    float hf = __builtin_bit_cast(float, ((unsigned)h) << 16);
    ushort l = rnd_bf16(x - hf);
    return (((unsigned)h) << 16) | l;
}
__device__ __forceinline__ float unpack_f32(unsigned u) {
    float hf = __builtin_bit_cast(float, u & 0xffff0000u);
    float lf = __builtin_bit_cast(float, u << 16);
    return hf + lf;
}
__device__ __forceinline__ void unpack8(const unsigned* p, bf16x8& h, bf16x8& l) {
    uint4 a = *(const uint4*)p;
    uint4 b = *(const uint4*)(p + 4);
    h[0] = (short)(a.x >> 16); l[0] = (short)(a.x & 0xffffu);
    h[1] = (short)(a.y >> 16); l[1] = (short)(a.y & 0xffffu);
    h[2] = (short)(a.z >> 16); l[2] = (short)(a.z & 0xffffu);
    h[3] = (short)(a.w >> 16); l[3] = (short)(a.w & 0xffffu);
    h[4] = (short)(b.x >> 16); l[4] = (short)(b.x & 0xffffu);
    h[5] = (short)(b.y >> 16); l[5] = (short)(b.y & 0xffffu);
    h[6] = (short)(b.z >> 16); l[6] = (short)(b.z & 0xffffu);
    h[7] = (short)(b.w >> 16); l[7] = (short)(b.w & 0xffffu);
}

// ---------------- CSR build ----------------
__global__ __launch_bounds__(256) void cnt_edge_kernel(const int* __restrict__ dst,
                                                       int* __restrict__ cnt, int E)
{
    int i = blockIdx.x * 256 + threadIdx.x;
    if (i < E) atomicAdd(&cnt[dst[i]], 1);
}

__global__ __launch_bounds__(256) void scan1_kernel(const int* __restrict__ cnt,
                                                    int* __restrict__ incl,
                                                    int* __restrict__ bsum, int N)
{
    __shared__ int s[256];
    int tid = threadIdx.x;
    int i = blockIdx.x * 256 + tid;
    s[tid] = (i < N) ? cnt[i] : 0;
    __syncthreads();
    #pragma unroll
    for (int off = 1; off < 256; off <<= 1) {
        int t = (tid >= off) ? s[tid - off] : 0;
        __syncthreads();
        s[tid] += t;
        __syncthreads();
    }
    if (i < N) incl[i] = s[tid];
    if (tid == 255) bsum[blockIdx.x] = s[255];
}

__global__ void scan2_kernel(int* __restrict__ bsum, int nb)   // 1 block, 64 threads
{
    int lane = threadIdx.x & 63;
    int run = 0;
    for (int base = 0; base < nb; base += 64) {
        int i = base + lane;
        int orig = (i < nb) ? bsum[i] : 0;
        int v = orig;
        #pragma unroll
        for (int off = 1; off < 64; off <<= 1) {
            int t = __shfl_up(v, off, 64);
            if (lane >= off) v += t;
        }
        if (i < nb) bsum[i] = run + v - orig;
        run += __shfl(v, 63, 64);
    }
}

__global__ __launch_bounds__(256) void scan3_kernel(const int* __restrict__ incl,
                                                    const int* __restrict__ cnt,
                                                    const int* __restrict__ bsum,
                                                    int* __restrict__ row_ptr,
                                                    int* __restrict__ cursor, int N)
{
    int i = blockIdx.x * 256 + threadIdx.x;
    if (i < N) {
        int v = incl[i] - cnt[i] + bsum[i >> 8];
        row_ptr[i] = v;
        cursor[i] = v;
    }
}

__global__ __launch_bounds__(256) void fill_kernel(const int* __restrict__ src,
                                                   const int* __restrict__ dst,
                                                   int* __restrict__ cursor,
                                                   int* __restrict__ colE, int E)
{
    int e = blockIdx.x * 256 + threadIdx.x;
    if (e < E) {
        int p = atomicAdd(&cursor[dst[e]], 1);
        colE[p] = src[e];
    }
}

__global__ __launch_bounds__(256) void dis_kernel(const int* __restrict__ cnt,
                                                  float* __restrict__ dis, int N)
{
    int i = blockIdx.x * 256 + threadIdx.x;
    if (i < N) dis[i] = rsqrtf((float)cnt[i] + 1.0f);
}

// ---------------- weight prep: Wt[col][k] packed-split u32 ----------------
__global__ __launch_bounds__(256) void wsplit_kernel(
    const float* __restrict__ W, int K, int Ncol, int KP,
    unsigned* __restrict__ Wp, int total)
{
    int idx = blockIdx.x * 256 + threadIdx.x;
    if (idx >= total) return;
    int col = idx / KP, k = idx - col * KP;
    float x = (k < K && col < Ncol) ? W[(size_t)k * Ncol + col] : 0.f;
    Wp[idx] = pack_split(x);
}

// cvec[col] = sum_k (b1[k]+b2[k]) * PW1[172+k][col]; cvec[176] = dot(b1, w2)
__global__ __launch_bounds__(256) void cvec_kernel(
    const float* __restrict__ PW1, const float* __restrict__ cb,
    const float* __restrict__ cw, float* __restrict__ cvec)
{
    int col = threadIdx.x;
    if (col < 176) {
        float s = 0.f;
        if (col < 172)
            for (int k = 0; k < 172; ++k)
                s += (cb[k] + cb[172 + k]) * PW1[(size_t)(172 + k) * 172 + col];
        cvec[col] = s;
    } else if (col == 176) {
        float c = 0.f;
        for (int k = 0; k < 172; ++k) c += cb[k] * cw[172 + k];
        cvec[176] = c;
    }
}

// ---------------- g0: embed -> [N,44] @ [44,128] + b, leaky -> xg packed ---
__global__ __launch_bounds__(256) void g0_kernel(
    const int* __restrict__ disc, const float* __restrict__ cont,
    const float* __restrict__ Wc, const float* __restrict__ bc,
    const float* __restrict__ W, const float* __restrict__ bias,
    unsigned* __restrict__ xgp, int N)
{
    constexpr int TM = 32, K = 44, RB = 8;
    __shared__ float Alds[TM][K];
    __shared__ float Wlds[K][128];
    const int tid = threadIdx.x, lane = tid & 63, wv = tid >> 6;
    const int row0 = blockIdx.x * TM;

    // stage embed (x_d | x_c) for TM rows
    for (int idx = tid; idx < TM * 38; idx += 256) {
        int r = idx / 38, j = idx - r * 38;
        int row = row0 + r;
        if (j == 0) {
            float o = 0.f;
            if (row < N) {
                const int* dr = disc + (size_t)row * 38;
                int best = dr[0], bi = 0;
                #pragma unroll
                for (int q = 1; q < 7; ++q) { int v = dr[q]; if (v > best) { best = v; bi = q; } }
                o = (float)bi;
            }
            Alds[r][0] = o;
        } else if (j >= 7) {
            Alds[r][j - 6] = (row < N) ? (float)disc[(size_t)row * 38 + j] : 0.f;
        }
    }
    for (int idx = tid; idx < TM * 12; idx += 256) {
        int r = idx / 12, q = idx - r * 12;
        int t = q >> 2, ch = q & 3;
        int row = row0 + r;
        float s = 0.f;
        if (row < N) {
            s = bc[ch];
            const float* cr = cont + (size_t)row * 90 + t * 30;
            #pragma unroll
            for (int j = 0; j < 30; ++j) s += cr[j] * Wc[j * 4 + ch];
        }
        Alds[r][32 + t * 4 + ch] = s;
    }
    for (int idx = tid; idx < K * 32; idx += 256) {
        int k = idx >> 5, c4 = idx & 31;
        ((float4*)&Wlds[k][0])[c4] = ((const float4*)W)[idx];
    }
    __syncthreads();

    float acc[RB][2];
    float b0 = bias[lane], b1 = bias[lane + 64];
    #pragma unroll
    for (int r = 0; r < RB; ++r) { acc[r][0] = b0; acc[r][1] = b1; }

    for (int k = 0; k < K; ++k) {
        float w0 = Wlds[k][lane], w1 = Wlds[k][lane + 64];
        #pragma unroll
        for (int r = 0; r < RB; ++r) {
            float a = Alds[wv * RB + r][k];
            acc[r][0] += a * w0;
            acc[r][1] += a * w1;
        }
    }
    #pragma unroll
    for (int r = 0; r < RB; ++r) {
        int row = row0 + wv * RB + r;
        if (row < N) {
            xgp[(size_t)row * 128 + lane]      = pack_split(leakyf(acc[r][0]));
            xgp[(size_t)row * 128 + lane + 64] = pack_split(leakyf(acc[r][1]));
        }
    }
}

// ---------------- gcn_fc: S[N,128] = xg(packed) @ G(packed)^T --------------
__global__ __launch_bounds__(256) void gcn_fc(
    const unsigned* __restrict__ xgp, const unsigned* __restrict__ Gp,
    float* __restrict__ S, int N)
{
    __shared__ unsigned Au[64][132];
    __shared__ unsigned Bu[128][36];
    const int tid = threadIdx.x, lane = tid & 63;
    const int msub = tid >> 6, l15 = lane & 15, kq = lane >> 4;
    const int row0 = blockIdx.x * 64;

    for (int idx = tid; idx < 2048; idx += 256) {
        int r = idx >> 5, q = idx & 31;
        int row = row0 + r;
        uint4 v = {0u, 0u, 0u, 0u};
        if (row < N) v = *(const uint4*)(xgp + (size_t)row * 128 + q * 4);
        *(uint4*)&Au[r][q * 4] = v;
    }

    f32x4 acc[8];
    #pragma unroll
    for (int t = 0; t < 8; ++t) acc[t] = (f32x4){0.f, 0.f, 0.f, 0.f};

    for (int c = 0; c < 4; ++c) {
        __syncthreads();
        for (int idx = tid; idx < 1024; idx += 256) {
            int col = idx >> 3, q = idx & 7;
            *(uint4*)&Bu[col][q * 4] = *(const uint4*)(Gp + (size_t)col * 128 + c * 32 + q * 4);
        }
        __syncthreads();
        bf16x8 ah, al;
        unpack8(&Au[msub * 16 + l15][c * 32 + kq * 8], ah, al);
        #pragma unroll
        for (int t = 0; t < 8; ++t) {
            bf16x8 bh, bl;
            unpack8(&Bu[t * 16 + l15][kq * 8], bh, bl);
            acc[t] = __builtin_amdgcn_mfma_f32_16x16x32_bf16(ah, bh, acc[t], 0, 0, 0);
            acc[t] = __builtin_amdgcn_mfma_f32_16x16x32_bf16(ah, bl, acc[t], 0, 0, 0);
            acc[t] = __builtin_amdgcn_mfma_f32_16x16x32_bf16(al, bh, acc[t], 0, 0, 0);
        }
    }

    #pragma unroll
    for (int t = 0; t < 8; ++t) {
        int col = t * 16 + l15;
        #pragma unroll
        for (int r = 0; r < 4; ++r) {
            int row = row0 + msub * 16 + kq * 4 + r;
            if (row < N) S[(size_t)row * 128 + col] = acc[t][r];
        }
    }
}

// ---------------- agg: gather CSR over S, fused self+bias+leaky -> xg -----
__global__ __launch_bounds__(256) void agg_kernel(
    const float* __restrict__ S, const int* __restrict__ colE,
    const int* __restrict__ rowp, const int* __restrict__ rend,
    const float* __restrict__ dis, const float* __restrict__ bias,
    unsigned* __restrict__ xgp, int N)
{
    int gw = (int)(((size_t)blockIdx.x * 256 + threadIdx.x) >> 6);
    int lane = threadIdx.x & 63;
    if (gw >= N) return;
    const float2* S2 = (const float2*)S;
    float dn = dis[gw];
    int st = rowp[gw], en = rend[gw];
    float ax = 0.f, ay = 0.f;
    for (int i = st; i < en; ++i) {
        int s = colE[i];
        float cf = dis[s] * dn;
        float2 v = S2[(size_t)s * 64 + lane];
        ax += v.x * cf;
        ay += v.y * cf;
    }
    float2 sv = S2[(size_t)gw * 64 + lane];
    float d2 = dn * dn;
    float2 bb = ((const float2*)bias)[lane];
    uint2 o;
    o.x = pack_split(leakyf(ax + sv.x * d2 + bb.x));
    o.y = pack_split(leakyf(ay + sv.y * d2 + bb.y));
    *(uint2*)(xgp + (size_t)gw * 128 + 2 * lane) = o;
}

// ---------------- stage x = [embed | xg] packed into LDS ----------------
__device__ __forceinline__ void stage_x(
    const int* __restrict__ disc, const float* __restrict__ cont,
    const float* __restrict__ Wc, const float* __restrict__ bc,
    const unsigned* __restrict__ xgp, unsigned (*Xu)[204],
    int row0, int N, int tid)
{
    for (int idx = tid; idx < 64 * 44; idx += 512) {
        int r = idx / 44, j = idx - r * 44;
        int row = row0 + r;
        float v = 0.f;
        if (row < N) {
            if (j == 0) {
                const int* dr = disc + (size_t)row * 38;
                int best = dr[0], bi = 0;
                #pragma unroll
                for (int q = 1; q < 7; ++q) { int t = dr[q]; if (t > best) { best = t; bi = q; } }
                v = (float)bi;
            } else if (j < 32) {
                v = (float)disc[(size_t)row * 38 + j + 6];
            } else {
                int q = j - 32, t = q >> 2, ch = q & 3;
                float s = bc[ch];
                const float* cr = cont + (size_t)row * 90 + t * 30;
                #pragma unroll
                for (int kk = 0; kk < 30; ++kk) s += cr[kk] * Wc[kk * 4 + ch];
                v = s;
            }
        }
        Xu[r][j] = pack_split(v);
    }
    for (int idx = tid; idx < 2048; idx += 512) {
        int r = idx >> 5, q = idx & 31;
        int row = row0 + r;
        uint4 v = {0u, 0u, 0u, 0u};
        if (row < N) v = *(const uint4*)(xgp + (size_t)row * 128 + q * 4);
        *(uint4*)&Xu[r][44 + q * 4] = v;
    }
    for (int idx = tid; idx < 64 * 32; idx += 512) {
        int r = idx >> 5, j = idx & 31;
        Xu[r][172 + j] = 0u;
    }
}

// GEMM pass from Xu (A) against packed Wp (B) -> acc[6] per wave (512 thr)
__device__ __forceinline__ void gemm_pass(
    const unsigned (*Xu)[204], unsigned (*Wl)[36], const unsigned* __restrict__ Wp,
    f32x4* acc, int msub, int half, int l15, int kq, int tid)
{
    #pragma unroll
    for (int t = 0; t < 6; ++t) acc[t] = (f32x4){0.f, 0.f, 0.f, 0.f};
    for (int c = 0; c < 6; ++c) {
        __syncthreads();
        for (int idx = tid; idx < 1536; idx += 512) {
            int col = idx >> 3, q = idx & 7;
            *(uint4*)&Wl[col][q * 4] = *(const uint4*)(Wp + (size_t)col * 192 + c * 32 + q * 4);
        }
        __syncthreads();
        bf16x8 ah, al;
        unpack8(&Xu[msub * 16 + l15][c * 32 + kq * 8], ah, al);
        #pragma unroll
        for (int t = 0; t < 6; ++t) {
            int col = half * 96 + t * 16 + l15;
            bf16x8 bh, bl;
            unpack8(&Wl[col][kq * 8], bh, bl);
            acc[t] = __builtin_amdgcn_mfma_f32_16x16x32_bf16(ah, bh, acc[t], 0, 0, 0);
            acc[t] = __builtin_amdgcn_mfma_f32_16x16x32_bf16(ah, bl, acc[t], 0, 0, 0);
            acc[t] = __builtin_amdgcn_mfma_f32_16x16x32_bf16(al, bh, acc[t], 0, 0, 0);
        }
    }
}

// ---------------- tail A: dnn1 -> dnn2 -> pred1a -> partA (bf16) ----------
__global__ __launch_bounds__(512) void dnnA_kernel(
    const int* __restrict__ disc, const float* __restrict__ cont,
    const float* __restrict__ Wc, const float* __restrict__ bc,
    const unsigned* __restrict__ xgp,
    const unsigned* __restrict__ W1p, const float* __restrict__ b1,
    const unsigned* __restrict__ W2p, const float* __restrict__ b2,
    const unsigned* __restrict__ P1ap, const float* __restrict__ pb1,
    ushort* __restrict__ partA, int N)
{
    __shared__ unsigned Xu[64][204];
    __shared__ unsigned Wl[192][36];
    const int tid = threadIdx.x, lane = tid & 63, wv = tid >> 6;
    const int msub = wv >> 1, half = wv & 1, l15 = lane & 15, kq = lane >> 4;
    const int row0 = blockIdx.x * 64;

    stage_x(disc, cont, Wc, bc, xgp, Xu, row0, N, tid);

    f32x4 acc[6];
    // dnn1
    gemm_pass(Xu, Wl, W1p, acc, msub, half, l15, kq, tid);
    __syncthreads();
    #pragma unroll
    for (int t = 0; t < 6; ++t) {
        int col = half * 96 + t * 16 + l15;
        if (col < 176) {
            #pragma unroll
            for (int r = 0; r < 4; ++r) {
                int row = msub * 16 + kq * 4 + r;
                float v = (col < 172) ? leakyf(acc[t][r] + b1[col]) : 0.f;
                Xu[row][col] = pack_split(v);
            }
        }
    }
    // dnn2
    gemm_pass(Xu, Wl, W2p, acc, msub, half, l15, kq, tid);
    __syncthreads();
    #pragma unroll
    for (int t = 0; t < 6; ++t) {
        int col = half * 96 + t * 16 + l15;
        if (col < 176) {
            #pragma unroll
            for (int r = 0; r < 4; ++r) {
                int row = msub * 16 + kq * 4 + r;
                float v = (col < 172) ? leakyf(acc[t][r] + b2[col]) : 0.f;
                Xu[row][col] = pack_split(v);
            }
        }
    }
    // pred1a -> partA (bf16 hi)
    gemm_pass(Xu, Wl, P1ap, acc, msub, half, l15, kq, tid);
    #pragma unroll
    for (int t = 0; t < 6; ++t) {
        int col = half * 96 + t * 16 + l15;
        if (col < 176) {
            #pragma unroll
            for (int r = 0; r < 4; ++r) {
                int grow = row0 + msub * 16 + kq * 4 + r;
                if (grow < N) {
                    float v = (col < 172) ? (acc[t][r] + pb1[col]) : 0.f;
                    partA[(size_t)grow * 176 + col] = rnd_bf16(v);
                }
            }
        }
    }
}

// ---------------- tail B: cross-alpha + pred1b + pred2 + sigmoid ----------
__global__ __launch_bounds__(512) void predB_kernel(
    const int* __restrict__ disc, const float* __restrict__ cont,
    const float* __restrict__ Wc, const float* __restrict__ bc,
    const unsigned* __restrict__ xgp,
    const unsigned* __restrict__ P1bp, const float* __restrict__ cw,
    const float* __restrict__ cvec, const ushort* __restrict__ partA,
    const float* __restrict__ pw2, const float* __restrict__ pb2,
    float* __restrict__ out, int N)
{
    __shared__ unsigned Xu[64][204];
    __shared__ unsigned Wl[192][36];
    __shared__ float als[64];
    __shared__ float partial[64][2];
    const int tid = threadIdx.x, lane = tid & 63, wv = tid >> 6;
    const int msub = wv >> 1, half = wv & 1, l15 = lane & 15, kq = lane >> 4;
    const int row0 = blockIdx.x * 64;

    stage_x(disc, cont, Wc, bc, xgp, Xu, row0, N, tid);
    __syncthreads();

    // per-row cross scalars: xl2 = alpha2*x0 + (b1+b2)
    {
        int row = tid >> 3, sub = tid & 7;
        float d1 = 0.f, d2 = 0.f;
        for (int col = sub; col < 172; col += 8) {
            float x = unpack_f32(Xu[row][col]);
            d1 += x * cw[col];
            d2 += x * cw[172 + col];
        }
        #pragma unroll
        for (int off = 1; off < 8; off <<= 1) {
            d1 += __shfl_xor(d1, off, 64);
            d2 += __shfl_xor(d2, off, 64);
        }
        if (sub == 0) {
            float a1 = 1.f + d1;
            float p2 = a1 * d2 + cvec[176];
            als[row] = a1 + p2;
        }
    }

    // G = x0 @ P1b
    f32x4 acc[6];
    gemm_pass(Xu, Wl, P1bp, acc, msub, half, l15, kq, tid);

    // epilogue: pre = partA + alpha*G + cvec -> leaky -> * pw2 -> reduce
    float part[4] = {0.f, 0.f, 0.f, 0.f};
    #pragma unroll
    for (int t = 0; t < 6; ++t) {
        int col = half * 96 + t * 16 + l15;
        if (col < 172) {
            float cv = cvec[col], w2v = pw2[col];
            #pragma unroll
            for (int r = 0; r < 4; ++r) {
                int row = msub * 16 + kq * 4 + r;
                int grow = row0 + row;
                if (grow < N) {
                    float pa = __builtin_bit_cast(float,
                        ((unsigned)partA[(size_t)grow * 176 + col]) << 16);
                    float pre = pa + als[row] * acc[t][r] + cv;
                    part[r] += leakyf(pre) * w2v;
                }
            }
        }
    }
    #pragma unroll
    for (int r = 0; r < 4; ++r) {
        #pragma unroll
        for (int off = 1; off < 16; off <<= 1)
            part[r] += __shfl_xor(part[r], off, 64);
    }
    if (l15 == 0) {
        #pragma unroll
        for (int r = 0; r < 4; ++r)
            partial[msub * 16 + kq * 4 + r][half] = part[r];
    }
    __syncthreads();
    if (tid < 64) {
        int grow = row0 + tid;
        if (grow < N) {
            float s = partial[tid][0] + partial[tid][1] + pb2[0];
            out[grow] = 1.f / (1.f + expf(-s));
        }
    }
}

extern "C" void kernel_launch(void* const* d_in, const int* in_sizes, int n_in,
                              void* d_out, int out_size, void* d_ws, size_t ws_size,
                              hipStream_t stream)
{
    const int*   disc    = (const int*)d_in[0];
    const float* cont    = (const float*)d_in[1];
    const int*   eidx    = (const int*)d_in[2];
    const float* emb_W   = (const float*)d_in[5];
    const float* emb_b   = (const float*)d_in[6];
    const float* g0_W    = (const float*)d_in[7];
    const float* g0_b    = (const float*)d_in[8];
    const float* gcn1_W  = (const float*)d_in[9];
    const float* gcn1_b  = (const float*)d_in[10];
    const float* gcn2_W  = (const float*)d_in[11];
    const float* gcn2_b  = (const float*)d_in[12];
    const float* dnn_W1  = (const float*)d_in[13];
    const float* dnn_b1  = (const float*)d_in[14];
    const float* dnn_W2  = (const float*)d_in[15];
    const float* dnn_b2  = (const float*)d_in[16];
    const float* cross_w = (const float*)d_in[17];
    const float* cross_b = (const float*)d_in[18];
    const float* pred_W1 = (const float*)d_in[19];
    const float* pred_b1 = (const float*)d_in[20];
    const float* pred_W2 = (const float*)d_in[21];
    const float* pred_b2 = (const float*)d_in[22];

    const int N = in_sizes[0] / 38;
    const int E = in_sizes[2] / 2;
    const int* src = eidx;
    const int* dst = eidx + E;

    // ---- workspace (~111 MB @ N=1e5, E=1.6e6) ----
    float* ws      = (float*)d_ws;
    unsigned* xgp  = (unsigned*)ws;                  // [N,128] packed split-bf16
    float* S       = ws + (size_t)128 * N;           // [N,128] f32 xw / [N,176] u16 partA
    float* dis     = ws + (size_t)256 * N;           // [N]
    int* cnt       = (int*)(ws + (size_t)257 * N);   // [N]
    int* rowp      = cnt + N;                        // [N]
    int* curs      = rowp + N;                       // [N] (incl, then cursor/end)
    int* bsum      = curs + N;                       // [512]
    int* colE      = bsum + 512;                     // [E]
    unsigned* wb   = (unsigned*)(((size_t)(colE + E) + 15) & ~(size_t)15);
    unsigned* G1p  = wb;              // 128*128
    unsigned* G2p  = G1p + 16384;
    unsigned* W1p  = G2p + 16384;     // 192*192
    unsigned* W2p  = W1p + 36864;
    unsigned* P1ap = W2p + 36864;
    unsigned* P1bp = P1ap + 36864;
    float* cvec    = (float*)(P1bp + 36864);         // [192]
    ushort* partA  = (ushort*)S;

    auto cdiv = [](int a, int b) { return (a + b - 1) / b; };
    const int nb = cdiv(N, 256);

    // weight prep
    wsplit_kernel<<<64, 256, 0, stream>>>(gcn1_W, 128, 128, 128, G1p, 16384);
    wsplit_kernel<<<64, 256, 0, stream>>>(gcn2_W, 128, 128, 128, G2p, 16384);
    wsplit_kernel<<<144, 256, 0, stream>>>(dnn_W1, 172, 172, 192, W1p, 36864);
    wsplit_kernel<<<144, 256, 0, stream>>>(dnn_W2, 172, 172, 192, W2p, 36864);
    wsplit_kernel<<<144, 256, 0, stream>>>(pred_W1, 172, 172, 192, P1ap, 36864);
    wsplit_kernel<<<144, 256, 0, stream>>>(pred_W1 + (size_t)172 * 172, 172, 172, 192, P1bp, 36864);
    cvec_kernel<<<1, 256, 0, stream>>>(pred_W1, cross_b, cross_w, cvec);

    // CSR build
    hipMemsetAsync(cnt, 0, (size_t)N * sizeof(int), stream);
    cnt_edge_kernel<<<cdiv(E, 256), 256, 0, stream>>>(dst, cnt, E);
    scan1_kernel<<<nb, 256, 0, stream>>>(cnt, curs, bsum, N);
    scan2_kernel<<<1, 64, 0, stream>>>(bsum, nb);
    scan3_kernel<<<nb, 256, 0, stream>>>(curs, cnt, bsum, rowp, curs, N);
    fill_kernel<<<cdiv(E, 256), 256, 0, stream>>>(src, dst, curs, colE, E);
    dis_kernel<<<cdiv(N, 256), 256, 0, stream>>>(cnt, dis, N);

    // g0 -> xg (packed)
    g0_kernel<<<cdiv(N, 32), 256, 0, stream>>>(disc, cont, emb_W, emb_b, g0_W, g0_b, xgp, N);

    // GCN layers
    gcn_fc<<<cdiv(N, 64), 256, 0, stream>>>(xgp, G1p, S, N);
    agg_kernel<<<cdiv(N, 4), 256, 0, stream>>>(S, colE, rowp, curs, dis, gcn1_b, xgp, N);
    gcn_fc<<<cdiv(N, 64), 256, 0, stream>>>(xgp, G2p, S, N);
    agg_kernel<<<cdiv(N, 4), 256, 0, stream>>>(S, colE, rowp, curs, dis, gcn2_b, xgp, N);

    // tail A: dnn1+dnn2+pred1a -> partA (overwrites S region)
    dnnA_kernel<<<cdiv(N, 64), 512, 0, stream>>>(
        disc, cont, emb_W, emb_b, xgp, W1p, dnn_b1, W2p, dnn_b2,
        P1ap, pred_b1, partA, N);

    // tail B: cross-alpha + pred1b + pred2 + sigmoid -> out
    predB_kernel<<<cdiv(N, 64), 512, 0, stream>>>(
        disc, cont, emb_W, emb_b, xgp, P1bp, cross_w, cvec, partA,
        pred_W2, pred_b2, (float*)d_out, N);
}

// Round 6
// 873.642 us; speedup vs baseline: 5.5371x; 1.1216x over previous
//
#include <hip/hip_runtime.h>
#include <math.h>

// ---------------------------------------------------------------------------
// DCN_89859305767621  Round 6:
//  - B-fragments loaded from L2 in pre-permuted fragment order (hi/lo planes):
//    no B unpack VALU, no B LDS staging, no per-chunk barriers
//  - A tiles planar bf16 hi/lo in LDS, conflict-free strides (136/200)
//  - GCN reordered by linearity: agg(x) then @W (+bias+leaky fused epilogue)
//  - agg gather unrolled x4; footprint held at ~111 MB (proven safe)
// ---------------------------------------------------------------------------

typedef __attribute__((ext_vector_type(8))) short bf16x8;
typedef __attribute__((ext_vector_type(4))) float f32x4;

__device__ __forceinline__ float leakyf(float v) { return v > 0.f ? v : 0.01f * v; }

__device__ __forceinline__ ushort rnd_bf16(float x) {
    unsigned u = __builtin_bit_cast(unsigned, x);
    return (ushort)((u + 0x8000u) >> 16);
}
__device__ __forceinline__ void split2(float x, ushort& h, ushort& l) {
    h = rnd_bf16(x);
    float hf = __builtin_bit_cast(float, ((unsigned)h) << 16);
    l = rnd_bf16(x - hf);
}
__device__ __forceinline__ unsigned pack_split(float x) {
    ushort h, l; split2(x, h, l);
    return (((unsigned)h) << 16) | l;
}
__device__ __forceinline__ float up_hi(unsigned u) { return __builtin_bit_cast(float, u & 0xffff0000u); }
__device__ __forceinline__ float up_lo(unsigned u) { return __builtin_bit_cast(float, u << 16); }
__device__ __forceinline__ float bf16f(ushort u) { return __builtin_bit_cast(float, ((unsigned)u) << 16); }

#define MFMA(a, b, c) __builtin_amdgcn_mfma_f32_16x16x32_bf16((a), (b), (c), 0, 0, 0)

// ---------------- CSR build ----------------
__global__ __launch_bounds__(256) void cnt_edge_kernel(const int* __restrict__ dst,
                                                       int* __restrict__ cnt, int E)
{
    int i = blockIdx.x * 256 + threadIdx.x;
    if (i < E) atomicAdd(&cnt[dst[i]], 1);
}

__global__ __launch_bounds__(256) void scan1_kernel(const int* __restrict__ cnt,
                                                    int* __restrict__ incl,
                                                    int* __restrict__ bsum, int N)
{
    __shared__ int s[256];
    int tid = threadIdx.x;
    int i = blockIdx.x * 256 + tid;
    s[tid] = (i < N) ? cnt[i] : 0;
    __syncthreads();
    #pragma unroll
    for (int off = 1; off < 256; off <<= 1) {
        int t = (tid >= off) ? s[tid - off] : 0;
        __syncthreads();
        s[tid] += t;
        __syncthreads();
    }
    if (i < N) incl[i] = s[tid];
    if (tid == 255) bsum[blockIdx.x] = s[255];
}

__global__ void scan2_kernel(int* __restrict__ bsum, int nb)   // 1 block, 64 threads
{
    int lane = threadIdx.x & 63;
    int run = 0;
    for (int base = 0; base < nb; base += 64) {
        int i = base + lane;
        int orig = (i < nb) ? bsum[i] : 0;
        int v = orig;
        #pragma unroll
        for (int off = 1; off < 64; off <<= 1) {
            int t = __shfl_up(v, off, 64);
            if (lane >= off) v += t;
        }
        if (i < nb) bsum[i] = run + v - orig;
        run += __shfl(v, 63, 64);
    }
}

__global__ __launch_bounds__(256) void scan3_kernel(const int* __restrict__ incl,
                                                    const int* __restrict__ cnt,
                                                    const int* __restrict__ bsum,
                                                    int* __restrict__ row_ptr,
                                                    int* __restrict__ cursor, int N)
{
    int i = blockIdx.x * 256 + threadIdx.x;
    if (i < N) {
        int v = incl[i] - cnt[i] + bsum[i >> 8];
        row_ptr[i] = v;
        cursor[i] = v;
    }
}

__global__ __launch_bounds__(256) void fill_kernel(const int* __restrict__ src,
                                                   const int* __restrict__ dst,
                                                   int* __restrict__ cursor,
                                                   int* __restrict__ colE, int E)
{
    int e = blockIdx.x * 256 + threadIdx.x;
    if (e < E) {
        int p = atomicAdd(&cursor[dst[e]], 1);
        colE[p] = src[e];
    }
}

__global__ __launch_bounds__(256) void dis_kernel(const int* __restrict__ cnt,
                                                  float* __restrict__ dis, int N)
{
    int i = blockIdx.x * 256 + threadIdx.x;
    if (i < N) dis[i] = rsqrtf((float)cnt[i] + 1.0f);
}

// ---------------- weight prep: fragment-order hi/lo planes ----------------
// layout idx = ((c*NT + t)*64 + lane)*8 + e ; lane=kq*16+l15 ; col=t*16+l15 ;
// k = c*32 + kq*8 + e  -> wave's frag load is 64 lanes x 16B fully coalesced.
__global__ __launch_bounds__(256) void wsplit_frag(
    const float* __restrict__ W, int K, int Ncol, int NT,
    ushort* __restrict__ Wh, ushort* __restrict__ Wl, int total)
{
    int idx = blockIdx.x * 256 + threadIdx.x;
    if (idx >= total) return;
    int e = idx & 7;
    int lane = (idx >> 3) & 63;
    int ct = idx >> 9;
    int t = ct % NT, c = ct / NT;
    int l15 = lane & 15, kq = lane >> 4;
    int col = t * 16 + l15;
    int k = c * 32 + kq * 8 + e;
    float x = (k < K && col < Ncol) ? W[(size_t)k * Ncol + col] : 0.f;
    ushort h, l; split2(x, h, l);
    Wh[idx] = h; Wl[idx] = l;
}

// cvec[col] = sum_k (b1[k]+b2[k]) * PW1[172+k][col]; cvec[176] = dot(b1, w2_cross)
__global__ __launch_bounds__(256) void cvec_kernel(
    const float* __restrict__ PW1, const float* __restrict__ cb,
    const float* __restrict__ cw, float* __restrict__ cvec)
{
    int col = threadIdx.x;
    if (col < 176) {
        float s = 0.f;
        if (col < 172)
            for (int k = 0; k < 172; ++k)
                s += (cb[k] + cb[172 + k]) * PW1[(size_t)(172 + k) * 172 + col];
        cvec[col] = s;
    } else if (col == 176) {
        float c = 0.f;
        for (int k = 0; k < 172; ++k) c += cb[k] * cw[172 + k];
        cvec[176] = c;
    }
}

// ---------------- g0: embed -> [N,44]@[44,128]+b, leaky -> xg packed ------
__global__ __launch_bounds__(256) void g0_kernel(
    const int* __restrict__ disc, const float* __restrict__ cont,
    const float* __restrict__ Wc, const float* __restrict__ bc,
    const float* __restrict__ W, const float* __restrict__ bias,
    unsigned* __restrict__ xgp, int N)
{
    constexpr int TM = 32, K = 44, RB = 8;
    __shared__ float Alds[TM][K];
    __shared__ float Wlds[K][128];
    const int tid = threadIdx.x, lane = tid & 63, wv = tid >> 6;
    const int row0 = blockIdx.x * TM;

    for (int idx = tid; idx < TM * 38; idx += 256) {
        int r = idx / 38, j = idx - r * 38;
        int row = row0 + r;
        if (j == 0) {
            float o = 0.f;
            if (row < N) {
                const int* dr = disc + (size_t)row * 38;
                int best = dr[0], bi = 0;
                #pragma unroll
                for (int q = 1; q < 7; ++q) { int v = dr[q]; if (v > best) { best = v; bi = q; } }
                o = (float)bi;
            }
            Alds[r][0] = o;
        } else if (j >= 7) {
            Alds[r][j - 6] = (row < N) ? (float)disc[(size_t)row * 38 + j] : 0.f;
        }
    }
    for (int idx = tid; idx < TM * 12; idx += 256) {
        int r = idx / 12, q = idx - r * 12;
        int t = q >> 2, ch = q & 3;
        int row = row0 + r;
        float s = 0.f;
        if (row < N) {
            s = bc[ch];
            const float* cr = cont + (size_t)row * 90 + t * 30;
            #pragma unroll
            for (int j = 0; j < 30; ++j) s += cr[j] * Wc[j * 4 + ch];
        }
        Alds[r][32 + t * 4 + ch] = s;
    }
    for (int idx = tid; idx < K * 32; idx += 256) {
        int k = idx >> 5, c4 = idx & 31;
        ((float4*)&Wlds[k][0])[c4] = ((const float4*)W)[idx];
    }
    __syncthreads();

    float acc[RB][2];
    float b0 = bias[lane], b1 = bias[lane + 64];
    #pragma unroll
    for (int r = 0; r < RB; ++r) { acc[r][0] = b0; acc[r][1] = b1; }

    for (int k = 0; k < K; ++k) {
        float w0 = Wlds[k][lane], w1 = Wlds[k][lane + 64];
        #pragma unroll
        for (int r = 0; r < RB; ++r) {
            float a = Alds[wv * RB + r][k];
            acc[r][0] += a * w0;
            acc[r][1] += a * w1;
        }
    }
    #pragma unroll
    for (int r = 0; r < RB; ++r) {
        int row = row0 + wv * RB + r;
        if (row < N) {
            xgp[(size_t)row * 128 + lane]      = pack_split(leakyf(acc[r][0]));
            xgp[(size_t)row * 128 + lane + 64] = pack_split(leakyf(acc[r][1]));
        }
    }
}

// ---------------- agg: Z = D^-1/2 (A+I) D^-1/2 x  (gather, packed io) -----
__global__ __launch_bounds__(256) void agg_kernel(
    const unsigned* __restrict__ xgp, const int* __restrict__ colE,
    const int* __restrict__ rowp, const int* __restrict__ rend,
    const float* __restrict__ dis, unsigned* __restrict__ Zp, int N)
{
    int gw = (int)(((size_t)blockIdx.x * 256 + threadIdx.x) >> 6);
    int lane = threadIdx.x & 63;
    if (gw >= N) return;
    const uint2* X2 = (const uint2*)xgp;
    float dn = dis[gw];
    int i = rowp[gw], en = rend[gw];
    float ax = 0.f, ay = 0.f;
    for (; i + 3 < en; i += 4) {
        int s0 = colE[i], s1 = colE[i + 1], s2 = colE[i + 2], s3 = colE[i + 3];
        float c0 = dis[s0] * dn, c1 = dis[s1] * dn, c2 = dis[s2] * dn, c3 = dis[s3] * dn;
        uint2 v0 = X2[(size_t)s0 * 64 + lane];
        uint2 v1 = X2[(size_t)s1 * 64 + lane];
        uint2 v2 = X2[(size_t)s2 * 64 + lane];
        uint2 v3 = X2[(size_t)s3 * 64 + lane];
        ax += (up_hi(v0.x) + up_lo(v0.x)) * c0; ay += (up_hi(v0.y) + up_lo(v0.y)) * c0;
        ax += (up_hi(v1.x) + up_lo(v1.x)) * c1; ay += (up_hi(v1.y) + up_lo(v1.y)) * c1;
        ax += (up_hi(v2.x) + up_lo(v2.x)) * c2; ay += (up_hi(v2.y) + up_lo(v2.y)) * c2;
        ax += (up_hi(v3.x) + up_lo(v3.x)) * c3; ay += (up_hi(v3.y) + up_lo(v3.y)) * c3;
    }
    for (; i < en; ++i) {
        int s = colE[i];
        float cf = dis[s] * dn;
        uint2 v = X2[(size_t)s * 64 + lane];
        ax += (up_hi(v.x) + up_lo(v.x)) * cf;
        ay += (up_hi(v.y) + up_lo(v.y)) * cf;
    }
    uint2 sv = X2[(size_t)gw * 64 + lane];
    float d2 = dn * dn;
    ax += (up_hi(sv.x) + up_lo(sv.x)) * d2;
    ay += (up_hi(sv.y) + up_lo(sv.y)) * d2;
    uint2 o;
    o.x = pack_split(ax);
    o.y = pack_split(ay);
    ((uint2*)Zp)[(size_t)gw * 64 + lane] = o;
}

// ---------------- gcn GEMM: xg = leaky(Z @ G + b), packed io --------------
__global__ __launch_bounds__(256) void gcn_gemm(
    const unsigned* __restrict__ Zp,
    const ushort* __restrict__ Bh, const ushort* __restrict__ Bl,
    const float* __restrict__ bias, unsigned* __restrict__ xgp, int N)
{
    __shared__ __attribute__((aligned(16))) ushort Ah[64][136];
    __shared__ __attribute__((aligned(16))) ushort Al[64][136];
    const int tid = threadIdx.x, lane = tid & 63, msub = tid >> 6;
    const int l15 = lane & 15, kq = lane >> 4;
    const int row0 = blockIdx.x * 64;

    for (int idx = tid; idx < 2048; idx += 256) {
        int r = idx >> 5, q = idx & 31;
        int row = row0 + r;
        uint4 v = {0u, 0u, 0u, 0u};
        if (row < N) v = *(const uint4*)(Zp + (size_t)row * 128 + q * 4);
        ushort4 h = { (ushort)(v.x >> 16), (ushort)(v.y >> 16),
                      (ushort)(v.z >> 16), (ushort)(v.w >> 16) };
        ushort4 l = { (ushort)v.x, (ushort)v.y, (ushort)v.z, (ushort)v.w };
        *(ushort4*)&Ah[r][q * 4] = h;
        *(ushort4*)&Al[r][q * 4] = l;
    }
    __syncthreads();

    f32x4 acc[8];
    #pragma unroll
    for (int t = 0; t < 8; ++t) acc[t] = (f32x4){0.f, 0.f, 0.f, 0.f};

    for (int c = 0; c < 4; ++c) {
        bf16x8 ah = *(const bf16x8*)&Ah[msub * 16 + l15][c * 32 + kq * 8];
        bf16x8 al = *(const bf16x8*)&Al[msub * 16 + l15][c * 32 + kq * 8];
        #pragma unroll
        for (int t = 0; t < 8; ++t) {
            const size_t base = (((size_t)c * 8 + t) * 64 + lane) * 8;
            bf16x8 bh = *(const bf16x8*)(Bh + base);
            bf16x8 bl = *(const bf16x8*)(Bl + base);
            acc[t] = MFMA(ah, bh, acc[t]);
            acc[t] = MFMA(ah, bl, acc[t]);
            acc[t] = MFMA(al, bh, acc[t]);
        }
    }

    #pragma unroll
    for (int t = 0; t < 8; ++t) {
        int col = t * 16 + l15;
        float bb = bias[col];
        #pragma unroll
        for (int r = 0; r < 4; ++r) {
            int row = row0 + msub * 16 + kq * 4 + r;
            if (row < N)
                xgp[(size_t)row * 128 + col] = pack_split(leakyf(acc[t][r] + bb));
        }
    }
}

// ---------------- fusion-tail helpers ----------------
__device__ __forceinline__ void stage_x(
    const int* __restrict__ disc, const float* __restrict__ cont,
    const float* __restrict__ Wc, const float* __restrict__ bc,
    const unsigned* __restrict__ xgp,
    ushort (*Ah)[200], ushort (*Al)[200], int row0, int N, int tid)
{
    for (int idx = tid; idx < 64 * 44; idx += 512) {
        int r = idx / 44, j = idx - r * 44;
        int row = row0 + r;
        float v = 0.f;
        if (row < N) {
            if (j == 0) {
                const int* dr = disc + (size_t)row * 38;
                int best = dr[0], bi = 0;
                #pragma unroll
                for (int q = 1; q < 7; ++q) { int t = dr[q]; if (t > best) { best = t; bi = q; } }
                v = (float)bi;
            } else if (j < 32) {
                v = (float)disc[(size_t)row * 38 + j + 6];
            } else {
                int q = j - 32, t = q >> 2, ch = q & 3;
                float s = bc[ch];
                const float* cr = cont + (size_t)row * 90 + t * 30;
                #pragma unroll
                for (int kk = 0; kk < 30; ++kk) s += cr[kk] * Wc[kk * 4 + ch];
                v = s;
            }
        }
        ushort h, l; split2(v, h, l);
        Ah[r][j] = h; Al[r][j] = l;
    }
    for (int idx = tid; idx < 2048; idx += 512) {
        int r = idx >> 5, q = idx & 31;
        int row = row0 + r;
        uint4 v = {0u, 0u, 0u, 0u};
        if (row < N) v = *(const uint4*)(xgp + (size_t)row * 128 + q * 4);
        ushort4 h = { (ushort)(v.x >> 16), (ushort)(v.y >> 16),
                      (ushort)(v.z >> 16), (ushort)(v.w >> 16) };
        ushort4 l = { (ushort)v.x, (ushort)v.y, (ushort)v.z, (ushort)v.w };
        *(ushort4*)&Ah[r][44 + q * 4] = h;
        *(ushort4*)&Al[r][44 + q * 4] = l;
    }
    for (int idx = tid; idx < 64 * 20; idx += 512) {
        int r = idx / 20, j = idx - r * 20;
        Ah[r][172 + j] = 0;
        Al[r][172 + j] = 0;
    }
}

// one GEMM pass: 6 K-chunks, 6 N-tiles per wave (cols half*96 + t*16 + l15)
__device__ __forceinline__ void gemm_pass_reg(
    const ushort (*Ah)[200], const ushort (*Al)[200],
    const ushort* __restrict__ Bh, const ushort* __restrict__ Bl,
    f32x4* acc, int msub, int half, int l15, int kq, int lane)
{
    #pragma unroll
    for (int t = 0; t < 6; ++t) acc[t] = (f32x4){0.f, 0.f, 0.f, 0.f};
    for (int c = 0; c < 6; ++c) {
        bf16x8 ah = *(const bf16x8*)&Ah[msub * 16 + l15][c * 32 + kq * 8];
        bf16x8 al = *(const bf16x8*)&Al[msub * 16 + l15][c * 32 + kq * 8];
        #pragma unroll
        for (int t = 0; t < 6; ++t) {
            const int tg = half * 6 + t;
            const size_t base = (((size_t)c * 12 + tg) * 64 + lane) * 8;
            bf16x8 bh = *(const bf16x8*)(Bh + base);
            bf16x8 bl = *(const bf16x8*)(Bl + base);
            acc[t] = MFMA(ah, bh, acc[t]);
            acc[t] = MFMA(ah, bl, acc[t]);
            acc[t] = MFMA(al, bh, acc[t]);
        }
    }
}

// ---------------- tail A: dnn1 -> dnn2 -> pred1a -> partA (bf16) ----------
__global__ __launch_bounds__(512) void dnnA_kernel(
    const int* __restrict__ disc, const float* __restrict__ cont,
    const float* __restrict__ Wc, const float* __restrict__ bc,
    const unsigned* __restrict__ xgp,
    const ushort* __restrict__ W1h, const ushort* __restrict__ W1l, const float* __restrict__ b1,
    const ushort* __restrict__ W2h, const ushort* __restrict__ W2l, const float* __restrict__ b2,
    const ushort* __restrict__ Pah, const ushort* __restrict__ Pal, const float* __restrict__ pb1,
    ushort* __restrict__ partA, int N)
{
    __shared__ __attribute__((aligned(16))) ushort Ah[64][200];
    __shared__ __attribute__((aligned(16))) ushort Al[64][200];
    const int tid = threadIdx.x, lane = tid & 63, wv = tid >> 6;
    const int msub = wv >> 1, half = wv & 1, l15 = lane & 15, kq = lane >> 4;
    const int row0 = blockIdx.x * 64;

    stage_x(disc, cont, Wc, bc, xgp, Ah, Al, row0, N, tid);
    __syncthreads();

    f32x4 acc[6];
    // dnn1
    gemm_pass_reg(Ah, Al, W1h, W1l, acc, msub, half, l15, kq, lane);
    __syncthreads();
    #pragma unroll
    for (int t = 0; t < 6; ++t) {
        int col = half * 96 + t * 16 + l15;
        #pragma unroll
        for (int r = 0; r < 4; ++r) {
            int row = msub * 16 + kq * 4 + r;
            float v = (col < 172) ? leakyf(acc[t][r] + b1[col]) : 0.f;
            ushort h, l; split2(v, h, l);
            Ah[row][col] = h; Al[row][col] = l;
        }
    }
    __syncthreads();
    // dnn2
    gemm_pass_reg(Ah, Al, W2h, W2l, acc, msub, half, l15, kq, lane);
    __syncthreads();
    #pragma unroll
    for (int t = 0; t < 6; ++t) {
        int col = half * 96 + t * 16 + l15;
        #pragma unroll
        for (int r = 0; r < 4; ++r) {
            int row = msub * 16 + kq * 4 + r;
            float v = (col < 172) ? leakyf(acc[t][r] + b2[col]) : 0.f;
            ushort h, l; split2(v, h, l);
            Ah[row][col] = h; Al[row][col] = l;
        }
    }
    __syncthreads();
    // pred1a -> partA (bf16 hi)
    gemm_pass_reg(Ah, Al, Pah, Pal, acc, msub, half, l15, kq, lane);
    #pragma unroll
    for (int t = 0; t < 6; ++t) {
        int col = half * 96 + t * 16 + l15;
        if (col < 176) {
            #pragma unroll
            for (int r = 0; r < 4; ++r) {
                int grow = row0 + msub * 16 + kq * 4 + r;
                if (grow < N) {
                    float v = (col < 172) ? (acc[t][r] + pb1[col]) : 0.f;
                    partA[(size_t)grow * 176 + col] = rnd_bf16(v);
                }
            }
        }
    }
}

// ---------------- tail B: cross-alpha + pred1b + pred2 + sigmoid ----------
__global__ __launch_bounds__(512) void predB_kernel(
    const int* __restrict__ disc, const float* __restrict__ cont,
    const float* __restrict__ Wc, const float* __restrict__ bc,
    const unsigned* __restrict__ xgp,
    const ushort* __restrict__ Pbh, const ushort* __restrict__ Pbl,
    const float* __restrict__ cw, const float* __restrict__ cvec,
    const ushort* __restrict__ partA,
    const float* __restrict__ pw2, const float* __restrict__ pb2,
    float* __restrict__ out, int N)
{
    __shared__ __attribute__((aligned(16))) ushort Ah[64][200];
    __shared__ __attribute__((aligned(16))) ushort Al[64][200];
    __shared__ float als[64];
    __shared__ float partial[64][2];
    const int tid = threadIdx.x, lane = tid & 63, wv = tid >> 6;
    const int msub = wv >> 1, half = wv & 1, l15 = lane & 15, kq = lane >> 4;
    const int row0 = blockIdx.x * 64;

    stage_x(disc, cont, Wc, bc, xgp, Ah, Al, row0, N, tid);
    __syncthreads();

    // per-row cross scalars: xl2 = alpha*x0 + (b1+b2)
    {
        int row = tid >> 3, sub = tid & 7;
        float d1 = 0.f, d2 = 0.f;
        for (int col = sub; col < 172; col += 8) {
            float x = bf16f(Ah[row][col]) + bf16f(Al[row][col]);
            d1 += x * cw[col];
            d2 += x * cw[172 + col];
        }
        #pragma unroll
        for (int off = 1; off < 8; off <<= 1) {
            d1 += __shfl_xor(d1, off, 64);
            d2 += __shfl_xor(d2, off, 64);
        }
        if (sub == 0) {
            float a1 = 1.f + d1;
            float p2 = a1 * d2 + cvec[176];
            als[row] = a1 + p2;
        }
    }
    __syncthreads();

    // G = x0 @ P1b
    f32x4 acc[6];
    gemm_pass_reg(Ah, Al, Pbh, Pbl, acc, msub, half, l15, kq, lane);

    // epilogue: pre = partA + alpha*G + cvec -> leaky -> * pw2 -> reduce
    float part[4] = {0.f, 0.f, 0.f, 0.f};
    #pragma unroll
    for (int t = 0; t < 6; ++t) {
        int col = half * 96 + t * 16 + l15;
        if (col < 172) {
            float cv = cvec[col], w2v = pw2[col];
            #pragma unroll
            for (int r = 0; r < 4; ++r) {
                int row = msub * 16 + kq * 4 + r;
                int grow = row0 + row;
                if (grow < N) {
                    float pa = bf16f(partA[(size_t)grow * 176 + col]);
                    float pre = pa + als[row] * acc[t][r] + cv;
                    part[r] += leakyf(pre) * w2v;
                }
            }
        }
    }
    #pragma unroll
    for (int r = 0; r < 4; ++r) {
        #pragma unroll
        for (int off = 1; off < 16; off <<= 1)
            part[r] += __shfl_xor(part[r], off, 64);
    }
    if (l15 == 0) {
        #pragma unroll
        for (int r = 0; r < 4; ++r)
            partial[msub * 16 + kq * 4 + r][half] = part[r];
    }
    __syncthreads();
    if (tid < 64) {
        int grow = row0 + tid;
        if (grow < N) {
            float s = partial[tid][0] + partial[tid][1] + pb2[0];
            out[grow] = 1.f / (1.f + expf(-s));
        }
    }
}

extern "C" void kernel_launch(void* const* d_in, const int* in_sizes, int n_in,
                              void* d_out, int out_size, void* d_ws, size_t ws_size,
                              hipStream_t stream)
{
    const int*   disc    = (const int*)d_in[0];
    const float* cont    = (const float*)d_in[1];
    const int*   eidx    = (const int*)d_in[2];
    const float* emb_W   = (const float*)d_in[5];
    const float* emb_b   = (const float*)d_in[6];
    const float* g0_W    = (const float*)d_in[7];
    const float* g0_b    = (const float*)d_in[8];
    const float* gcn1_W  = (const float*)d_in[9];
    const float* gcn1_b  = (const float*)d_in[10];
    const float* gcn2_W  = (const float*)d_in[11];
    const float* gcn2_b  = (const float*)d_in[12];
    const float* dnn_W1  = (const float*)d_in[13];
    const float* dnn_b1  = (const float*)d_in[14];
    const float* dnn_W2  = (const float*)d_in[15];
    const float* dnn_b2  = (const float*)d_in[16];
    const float* cross_w = (const float*)d_in[17];
    const float* cross_b = (const float*)d_in[18];
    const float* pred_W1 = (const float*)d_in[19];
    const float* pred_b1 = (const float*)d_in[20];
    const float* pred_W2 = (const float*)d_in[21];
    const float* pred_b2 = (const float*)d_in[22];

    const int N = in_sizes[0] / 38;
    const int E = in_sizes[2] / 2;
    const int* src = eidx;
    const int* dst = eidx + E;

    // ---- workspace (~111 MB @ N=1e5, E=1.6e6) ----
    unsigned* xgp = (unsigned*)d_ws;                  // [N,128] packed split-bf16
    unsigned* Zp  = xgp + (size_t)128 * N;            // [N,128] packed agg / partA u16
    float* dis    = (float*)(Zp + (size_t)128 * N);   // [N]
    int* cnt      = (int*)(dis + N);                  // [N]
    int* rowp     = cnt + N;                          // [N]
    int* curs     = rowp + N;                         // [N] (incl, then cursor/end)
    int* bsum     = curs + N;                         // [512]
    int* colE     = bsum + 512;                       // [E]
    ushort* wb    = (ushort*)(((size_t)(colE + E) + 15) & ~(size_t)15);
    ushort* G1h = wb;            ushort* G1l = G1h + 16384;   // 4*8*512
    ushort* G2h = G1l + 16384;   ushort* G2l = G2h + 16384;
    ushort* W1h = G2l + 16384;   ushort* W1l = W1h + 36864;   // 6*12*512
    ushort* W2h = W1l + 36864;   ushort* W2l = W2h + 36864;
    ushort* Pah = W2l + 36864;   ushort* Pal = Pah + 36864;
    ushort* Pbh = Pal + 36864;   ushort* Pbl = Pbh + 36864;
    float* cvec = (float*)(Pbl + 36864);              // [192]
    ushort* partA = (ushort*)Zp;                      // [N,176] after gcn done

    auto cdiv = [](int a, int b) { return (a + b - 1) / b; };
    const int nb = cdiv(N, 256);

    // weight prep (fragment-order hi/lo planes)
    wsplit_frag<<<64, 256, 0, stream>>>(gcn1_W, 128, 128, 8, G1h, G1l, 16384);
    wsplit_frag<<<64, 256, 0, stream>>>(gcn2_W, 128, 128, 8, G2h, G2l, 16384);
    wsplit_frag<<<144, 256, 0, stream>>>(dnn_W1, 172, 172, 12, W1h, W1l, 36864);
    wsplit_frag<<<144, 256, 0, stream>>>(dnn_W2, 172, 172, 12, W2h, W2l, 36864);
    wsplit_frag<<<144, 256, 0, stream>>>(pred_W1, 172, 172, 12, Pah, Pal, 36864);
    wsplit_frag<<<144, 256, 0, stream>>>(pred_W1 + (size_t)172 * 172, 172, 172, 12, Pbh, Pbl, 36864);
    cvec_kernel<<<1, 256, 0, stream>>>(pred_W1, cross_b, cross_w, cvec);

    // CSR build
    hipMemsetAsync(cnt, 0, (size_t)N * sizeof(int), stream);
    cnt_edge_kernel<<<cdiv(E, 256), 256, 0, stream>>>(dst, cnt, E);
    scan1_kernel<<<nb, 256, 0, stream>>>(cnt, curs, bsum, N);
    scan2_kernel<<<1, 64, 0, stream>>>(bsum, nb);
    scan3_kernel<<<nb, 256, 0, stream>>>(curs, cnt, bsum, rowp, curs, N);
    fill_kernel<<<cdiv(E, 256), 256, 0, stream>>>(src, dst, curs, colE, E);
    dis_kernel<<<cdiv(N, 256), 256, 0, stream>>>(cnt, dis, N);

    // g0 -> xg (packed)
    g0_kernel<<<cdiv(N, 32), 256, 0, stream>>>(disc, cont, emb_W, emb_b, g0_W, g0_b, xgp, N);

    // GCN layer 1 (agg first, then GEMM — linearity)
    agg_kernel<<<cdiv(N, 4), 256, 0, stream>>>(xgp, colE, rowp, curs, dis, Zp, N);
    gcn_gemm<<<cdiv(N, 64), 256, 0, stream>>>(Zp, G1h, G1l, gcn1_b, xgp, N);
    // GCN layer 2
    agg_kernel<<<cdiv(N, 4), 256, 0, stream>>>(xgp, colE, rowp, curs, dis, Zp, N);
    gcn_gemm<<<cdiv(N, 64), 256, 0, stream>>>(Zp, G2h, G2l, gcn2_b, xgp, N);

    // tail A: dnn1+dnn2+pred1a -> partA (overwrites Zp region)
    dnnA_kernel<<<cdiv(N, 64), 512, 0, stream>>>(
        disc, cont, emb_W, emb_b, xgp,
        W1h, W1l, dnn_b1, W2h, W2l, dnn_b2, Pah, Pal, pred_b1, partA, N);

    // tail B: cross-alpha + pred1b + pred2 + sigmoid -> out
    predB_kernel<<<cdiv(N, 64), 512, 0, stream>>>(
        disc, cont, emb_W, emb_b, xgp, Pbh, Pbl, cross_w, cvec, partA,
        pred_W2, pred_b2, (float*)d_out, N);
}

// Round 7
// 674.218 us; speedup vs baseline: 7.1749x; 1.2958x over previous
//
#include <hip/hip_runtime.h>
#include <math.h>

// ---------------------------------------------------------------------------
// DCN_89859305767621  Round 7:
//  - fp16 single-MFMA GEMMs (16x16x32_f16): 3x fewer MFMAs, half B-traffic,
//    single-plane A in LDS; xg/Z plain f32 (no pack/unpack anywhere)
//  - dnnA+predB fused into one tail kernel (no partA round-trip)
//  - explicit B-fragment register double-buffer prefetch; VGPR cap 128
//  - agg: per-edge coeff fused into int2 {src, coeff} at fill time
// ---------------------------------------------------------------------------

typedef __attribute__((ext_vector_type(8))) _Float16 f16x8;
typedef __attribute__((ext_vector_type(4))) _Float16 f16x4;
typedef __attribute__((ext_vector_type(4))) float f32x4;

__device__ __forceinline__ float leakyf(float v) { return v > 0.f ? v : 0.01f * v; }

#define MFMA16(a, b, c) __builtin_amdgcn_mfma_f32_16x16x32_f16((a), (b), (c), 0, 0, 0)

// ---------------- CSR build ----------------
__global__ __launch_bounds__(256) void cnt_edge_kernel(const int* __restrict__ dst,
                                                       int* __restrict__ cnt, int E)
{
    int i = blockIdx.x * 256 + threadIdx.x;
    if (i < E) atomicAdd(&cnt[dst[i]], 1);
}

__global__ __launch_bounds__(256) void scan1_kernel(const int* __restrict__ cnt,
                                                    int* __restrict__ incl,
                                                    int* __restrict__ bsum, int N)
{
    __shared__ int s[256];
    int tid = threadIdx.x;
    int i = blockIdx.x * 256 + tid;
    s[tid] = (i < N) ? cnt[i] : 0;
    __syncthreads();
    #pragma unroll
    for (int off = 1; off < 256; off <<= 1) {
        int t = (tid >= off) ? s[tid - off] : 0;
        __syncthreads();
        s[tid] += t;
        __syncthreads();
    }
    if (i < N) incl[i] = s[tid];
    if (tid == 255) bsum[blockIdx.x] = s[255];
}

__global__ void scan2_kernel(int* __restrict__ bsum, int nb)   // 1 block, 64 threads
{
    int lane = threadIdx.x & 63;
    int run = 0;
    for (int base = 0; base < nb; base += 64) {
        int i = base + lane;
        int orig = (i < nb) ? bsum[i] : 0;
        int v = orig;
        #pragma unroll
        for (int off = 1; off < 64; off <<= 1) {
            int t = __shfl_up(v, off, 64);
            if (lane >= off) v += t;
        }
        if (i < nb) bsum[i] = run + v - orig;
        run += __shfl(v, 63, 64);
    }
}

__global__ __launch_bounds__(256) void scan3_kernel(const int* __restrict__ incl,
                                                    const int* __restrict__ cnt,
                                                    const int* __restrict__ bsum,
                                                    int* __restrict__ row_ptr,
                                                    int* __restrict__ cursor, int N)
{
    int i = blockIdx.x * 256 + threadIdx.x;
    if (i < N) {
        int v = incl[i] - cnt[i] + bsum[i >> 8];
        row_ptr[i] = v;
        cursor[i] = v;
    }
}

__global__ __launch_bounds__(256) void dis_kernel(const int* __restrict__ cnt,
                                                  float* __restrict__ dis, int N)
{
    int i = blockIdx.x * 256 + threadIdx.x;
    if (i < N) dis[i] = rsqrtf((float)cnt[i] + 1.0f);
}

// fill CSR adjacency with fused edge coefficient: colcf[p] = {src, dis_s*dis_d}
__global__ __launch_bounds__(256) void fill_kernel(const int* __restrict__ src,
                                                   const int* __restrict__ dst,
                                                   const float* __restrict__ dis,
                                                   int* __restrict__ cursor,
                                                   int2* __restrict__ colcf, int E)
{
    int e = blockIdx.x * 256 + threadIdx.x;
    if (e < E) {
        int s = src[e], d = dst[e];
        int p = atomicAdd(&cursor[d], 1);
        colcf[p] = make_int2(s, __float_as_int(dis[s] * dis[d]));
    }
}

// ---------------- weight prep: fragment-order fp16 plane ----------------
// idx = ((c*NT + t)*64 + lane)*8 + e ; col = t*16 + (lane&15) ;
// k = c*32 + (lane>>4)*8 + e  -> per-wave frag load = 64 lanes x 16B coalesced.
__global__ __launch_bounds__(256) void wsplit_frag(
    const float* __restrict__ W, int K, int Ncol, int NT,
    _Float16* __restrict__ Wf, int total)
{
    int idx = blockIdx.x * 256 + threadIdx.x;
    if (idx >= total) return;
    int e = idx & 7;
    int lane = (idx >> 3) & 63;
    int ct = idx >> 9;
    int t = ct % NT, c = ct / NT;
    int col = t * 16 + (lane & 15);
    int k = c * 32 + (lane >> 4) * 8 + e;
    float x = (k < K && col < Ncol) ? W[(size_t)k * Ncol + col] : 0.f;
    Wf[idx] = (_Float16)x;
}

// cvec[col] = sum_k (b1[k]+b2[k]) * PW1[172+k][col]; cvec[176] = dot(b1, w2_cross)
__global__ __launch_bounds__(256) void cvec_kernel(
    const float* __restrict__ PW1, const float* __restrict__ cb,
    const float* __restrict__ cw, float* __restrict__ cvec)
{
    int col = threadIdx.x;
    if (col < 176) {
        float s = 0.f;
        if (col < 172)
            for (int k = 0; k < 172; ++k)
                s += (cb[k] + cb[172 + k]) * PW1[(size_t)(172 + k) * 172 + col];
        cvec[col] = s;
    } else if (col == 176) {
        float c = 0.f;
        for (int k = 0; k < 172; ++k) c += cb[k] * cw[172 + k];
        cvec[176] = c;
    }
}

// ---------------- g0: embed -> [N,44]@[44,128]+b, leaky -> xg f32 ---------
__global__ __launch_bounds__(256) void g0_kernel(
    const int* __restrict__ disc, const float* __restrict__ cont,
    const float* __restrict__ Wc, const float* __restrict__ bc,
    const float* __restrict__ W, const float* __restrict__ bias,
    float* __restrict__ xg, int N)
{
    constexpr int TM = 32, K = 44, RB = 8;
    __shared__ float Alds[TM][K];
    __shared__ float Wlds[K][128];
    const int tid = threadIdx.x, lane = tid & 63, wv = tid >> 6;
    const int row0 = blockIdx.x * TM;

    for (int idx = tid; idx < TM * 38; idx += 256) {
        int r = idx / 38, j = idx - r * 38;
        int row = row0 + r;
        if (j == 0) {
            float o = 0.f;
            if (row < N) {
                const int* dr = disc + (size_t)row * 38;
                int best = dr[0], bi = 0;
                #pragma unroll
                for (int q = 1; q < 7; ++q) { int v = dr[q]; if (v > best) { best = v; bi = q; } }
                o = (float)bi;
            }
            Alds[r][0] = o;
        } else if (j >= 7) {
            Alds[r][j - 6] = (row < N) ? (float)disc[(size_t)row * 38 + j] : 0.f;
        }
    }
    for (int idx = tid; idx < TM * 12; idx += 256) {
        int r = idx / 12, q = idx - r * 12;
        int t = q >> 2, ch = q & 3;
        int row = row0 + r;
        float s = 0.f;
        if (row < N) {
            s = bc[ch];
            const float* cr = cont + (size_t)row * 90 + t * 30;
            #pragma unroll
            for (int j = 0; j < 30; ++j) s += cr[j] * Wc[j * 4 + ch];
        }
        Alds[r][32 + t * 4 + ch] = s;
    }
    for (int idx = tid; idx < K * 32; idx += 256) {
        int k = idx >> 5, c4 = idx & 31;
        ((float4*)&Wlds[k][0])[c4] = ((const float4*)W)[idx];
    }
    __syncthreads();

    float acc[RB][2];
    float b0 = bias[lane], b1 = bias[lane + 64];
    #pragma unroll
    for (int r = 0; r < RB; ++r) { acc[r][0] = b0; acc[r][1] = b1; }

    for (int k = 0; k < K; ++k) {
        float w0 = Wlds[k][lane], w1 = Wlds[k][lane + 64];
        #pragma unroll
        for (int r = 0; r < RB; ++r) {
            float a = Alds[wv * RB + r][k];
            acc[r][0] += a * w0;
            acc[r][1] += a * w1;
        }
    }
    #pragma unroll
    for (int r = 0; r < RB; ++r) {
        int row = row0 + wv * RB + r;
        if (row < N) {
            xg[(size_t)row * 128 + lane]      = leakyf(acc[r][0]);
            xg[(size_t)row * 128 + lane + 64] = leakyf(acc[r][1]);
        }
    }
}

// ---------------- agg: Z = D^-1/2 (A+I) D^-1/2 x   (gather, f32) ----------
__global__ __launch_bounds__(256) void agg_kernel(
    const float* __restrict__ xg, const int2* __restrict__ colcf,
    const int* __restrict__ rowp, const int* __restrict__ rend,
    const float* __restrict__ dis, float* __restrict__ Z, int N)
{
    int gw = (int)(((size_t)blockIdx.x * 256 + threadIdx.x) >> 6);
    int lane = threadIdx.x & 63;
    if (gw >= N) return;
    const float2* X2 = (const float2*)xg;
    int i = rowp[gw], en = rend[gw];
    float ax = 0.f, ay = 0.f;
    for (; i + 3 < en; i += 4) {
        int2 e0 = colcf[i],     e1 = colcf[i + 1];
        int2 e2 = colcf[i + 2], e3 = colcf[i + 3];
        float2 v0 = X2[(size_t)e0.x * 64 + lane];
        float2 v1 = X2[(size_t)e1.x * 64 + lane];
        float2 v2 = X2[(size_t)e2.x * 64 + lane];
        float2 v3 = X2[(size_t)e3.x * 64 + lane];
        float c0 = __int_as_float(e0.y), c1 = __int_as_float(e1.y);
        float c2 = __int_as_float(e2.y), c3 = __int_as_float(e3.y);
        ax += v0.x * c0; ay += v0.y * c0;
        ax += v1.x * c1; ay += v1.y * c1;
        ax += v2.x * c2; ay += v2.y * c2;
        ax += v3.x * c3; ay += v3.y * c3;
    }
    for (; i < en; ++i) {
        int2 e = colcf[i];
        float2 v = X2[(size_t)e.x * 64 + lane];
        float cf = __int_as_float(e.y);
        ax += v.x * cf; ay += v.y * cf;
    }
    float dn = dis[gw];
    float2 sv = X2[(size_t)gw * 64 + lane];
    float d2 = dn * dn;
    float2 o;
    o.x = ax + sv.x * d2;
    o.y = ay + sv.y * d2;
    ((float2*)Z)[(size_t)gw * 64 + lane] = o;
}

// ---------------- gcn GEMM: xg = leaky(Z @ G + b), fp16 MFMA --------------
__global__ __launch_bounds__(256, 4) void gcn_gemm(
    const float* __restrict__ Z, const _Float16* __restrict__ B,
    const float* __restrict__ bias, float* __restrict__ xg, int N)
{
    __shared__ __attribute__((aligned(16))) _Float16 Xs[64][136];
    const int tid = threadIdx.x, lane = tid & 63, msub = tid >> 6;
    const int l15 = lane & 15, kq = lane >> 4;
    const int row0 = blockIdx.x * 64;

    for (int idx = tid; idx < 2048; idx += 256) {
        int r = idx >> 5, q = idx & 31;
        int row = row0 + r;
        float4 v = make_float4(0.f, 0.f, 0.f, 0.f);
        if (row < N) v = *(const float4*)(Z + (size_t)row * 128 + q * 4);
        f16x4 h = { (_Float16)v.x, (_Float16)v.y, (_Float16)v.z, (_Float16)v.w };
        *(f16x4*)&Xs[r][q * 4] = h;
    }
    __syncthreads();

    f32x4 acc[8];
    #pragma unroll
    for (int t = 0; t < 8; ++t) acc[t] = (f32x4){0.f, 0.f, 0.f, 0.f};

    f16x8 bc[8];
    #pragma unroll
    for (int t = 0; t < 8; ++t)
        bc[t] = *(const f16x8*)(B + (((size_t)t) * 64 + lane) * 8);

    #pragma unroll
    for (int c = 0; c < 4; ++c) {
        f16x8 a = *(const f16x8*)&Xs[msub * 16 + l15][c * 32 + kq * 8];
        f16x8 bn[8];
        #pragma unroll
        for (int t = 0; t < 8; ++t)
            bn[t] = (c < 3) ? *(const f16x8*)(B + (((size_t)(c + 1) * 8 + t) * 64 + lane) * 8)
                            : bc[t];
        #pragma unroll
        for (int t = 0; t < 8; ++t) acc[t] = MFMA16(a, bc[t], acc[t]);
        #pragma unroll
        for (int t = 0; t < 8; ++t) bc[t] = bn[t];
    }

    #pragma unroll
    for (int t = 0; t < 8; ++t) {
        int col = t * 16 + l15;
        float bb = bias[col];
        #pragma unroll
        for (int r = 0; r < 4; ++r) {
            int row = row0 + msub * 16 + kq * 4 + r;
            if (row < N)
                xg[(size_t)row * 128 + col] = leakyf(acc[t][r] + bb);
        }
    }
}

// ---------------- tail helpers ----------------
__device__ __forceinline__ void stage_x16(
    const int* __restrict__ disc, const float* __restrict__ cont,
    const float* __restrict__ Wc, const float* __restrict__ bc,
    const float* __restrict__ xg, _Float16 (*Xs)[200], int row0, int N, int tid)
{
    for (int idx = tid; idx < 64 * 44; idx += 512) {
        int r = idx / 44, j = idx - r * 44;
        int row = row0 + r;
        float v = 0.f;
        if (row < N) {
            if (j == 0) {
                const int* dr = disc + (size_t)row * 38;
                int best = dr[0], bi = 0;
                #pragma unroll
                for (int q = 1; q < 7; ++q) { int t = dr[q]; if (t > best) { best = t; bi = q; } }
                v = (float)bi;
            } else if (j < 32) {
                v = (float)disc[(size_t)row * 38 + j + 6];
            } else {
                int q = j - 32, t = q >> 2, ch = q & 3;
                float s = bc[ch];
                const float* cr = cont + (size_t)row * 90 + t * 30;
                #pragma unroll
                for (int kk = 0; kk < 30; ++kk) s += cr[kk] * Wc[kk * 4 + ch];
                v = s;
            }
        }
        Xs[r][j] = (_Float16)v;
    }
    for (int idx = tid; idx < 2048; idx += 512) {
        int r = idx >> 5, q = idx & 31;
        int row = row0 + r;
        float4 v = make_float4(0.f, 0.f, 0.f, 0.f);
        if (row < N) v = *(const float4*)(xg + (size_t)row * 128 + q * 4);
        f16x4 h = { (_Float16)v.x, (_Float16)v.y, (_Float16)v.z, (_Float16)v.w };
        *(f16x4*)&Xs[r][44 + q * 4] = h;
    }
    for (int idx = tid; idx < 64 * 20; idx += 512) {
        int r = idx / 20, j = idx - r * 20;
        Xs[r][172 + j] = (_Float16)0.f;
    }
}

// one pass: 6 K-chunks x 6 N-tiles per wave (cols half*96 + t*16 + l15),
// B-fragments register-double-buffered straight from L2.
__device__ __forceinline__ void gemm_pass6(
    const _Float16 (*X)[200], const _Float16* __restrict__ B,
    f32x4* acc, int msub, int half, int l15, int kq, int lane)
{
    #pragma unroll
    for (int t = 0; t < 6; ++t) acc[t] = (f32x4){0.f, 0.f, 0.f, 0.f};
    f16x8 bc[6];
    #pragma unroll
    for (int t = 0; t < 6; ++t)
        bc[t] = *(const f16x8*)(B + (((size_t)(half * 6 + t)) * 64 + lane) * 8);
    #pragma unroll
    for (int c = 0; c < 6; ++c) {
        f16x8 a = *(const f16x8*)&X[msub * 16 + l15][c * 32 + kq * 8];
        f16x8 bn[6];
        #pragma unroll
        for (int t = 0; t < 6; ++t)
            bn[t] = (c < 5) ? *(const f16x8*)(B + (((size_t)(c + 1) * 12 + half * 6 + t) * 64 + lane) * 8)
                            : bc[t];
        #pragma unroll
        for (int t = 0; t < 6; ++t) acc[t] = MFMA16(a, bc[t], acc[t]);
        #pragma unroll
        for (int t = 0; t < 6; ++t) bc[t] = bn[t];
    }
}

// ---------------- fused tail: dnn1+dnn2+pred1(a,b)+cross+pred2+sigmoid ----
__global__ __launch_bounds__(512, 4) void tail_kernel(
    const int* __restrict__ disc, const float* __restrict__ cont,
    const float* __restrict__ Wc, const float* __restrict__ bc,
    const float* __restrict__ xg,
    const _Float16* __restrict__ W1, const float* __restrict__ b1,
    const _Float16* __restrict__ W2, const float* __restrict__ b2,
    const _Float16* __restrict__ Pa, const _Float16* __restrict__ Pb,
    const float* __restrict__ pb1,
    const float* __restrict__ cw, const float* __restrict__ cvec,
    const float* __restrict__ pw2, const float* __restrict__ pb2,
    float* __restrict__ out, int N)
{
    __shared__ __attribute__((aligned(16))) _Float16 Xs[64][200];
    __shared__ __attribute__((aligned(16))) _Float16 Ts[64][200];
    __shared__ float als[64];
    __shared__ float partial[64][2];
    const int tid = threadIdx.x, lane = tid & 63, wv = tid >> 6;
    const int msub = wv >> 1, half = wv & 1, l15 = lane & 15, kq = lane >> 4;
    const int row0 = blockIdx.x * 64;

    stage_x16(disc, cont, Wc, bc, xg, Xs, row0, N, tid);
    __syncthreads();

    // per-row cross scalars: xl2 = als*x0 + (b1c+b2c)
    {
        int row = tid >> 3, sub = tid & 7;
        float d1 = 0.f, d2 = 0.f;
        for (int col = sub; col < 172; col += 8) {
            float x = (float)Xs[row][col];
            d1 += x * cw[col];
            d2 += x * cw[172 + col];
        }
        #pragma unroll
        for (int off = 1; off < 8; off <<= 1) {
            d1 += __shfl_xor(d1, off, 64);
            d2 += __shfl_xor(d2, off, 64);
        }
        if (sub == 0) {
            float a1 = 1.f + d1;
            als[row] = a1 + a1 * d2 + cvec[176];
        }
    }

    f32x4 accA[6], accB[6];

    // dnn1: Xs -> Ts
    gemm_pass6(Xs, W1, accA, msub, half, l15, kq, lane);
    #pragma unroll
    for (int t = 0; t < 6; ++t) {
        int col = half * 96 + t * 16 + l15;
        #pragma unroll
        for (int r = 0; r < 4; ++r) {
            int row = msub * 16 + kq * 4 + r;
            float v = (col < 172) ? leakyf(accA[t][r] + b1[col]) : 0.f;
            Ts[row][col] = (_Float16)v;
        }
    }
    __syncthreads();
    // dnn2: Ts -> Ts (in place)
    gemm_pass6(Ts, W2, accA, msub, half, l15, kq, lane);
    __syncthreads();
    #pragma unroll
    for (int t = 0; t < 6; ++t) {
        int col = half * 96 + t * 16 + l15;
        #pragma unroll
        for (int r = 0; r < 4; ++r) {
            int row = msub * 16 + kq * 4 + r;
            float v = (col < 172) ? leakyf(accA[t][r] + b2[col]) : 0.f;
            Ts[row][col] = (_Float16)v;
        }
    }
    __syncthreads();

    // pred1: accA = xdeep@Pa (from Ts), accB = x0@Pb (from Xs)
    gemm_pass6(Ts, Pa, accA, msub, half, l15, kq, lane);
    gemm_pass6(Xs, Pb, accB, msub, half, l15, kq, lane);

    // epilogue: pre = accA + pb1 + als*accB + cvec -> leaky -> . pw2 -> sigmoid
    float part[4] = {0.f, 0.f, 0.f, 0.f};
    #pragma unroll
    for (int t = 0; t < 6; ++t) {
        int col = half * 96 + t * 16 + l15;
        if (col < 172) {
            float cv = cvec[col] + pb1[col], w2v = pw2[col];
            #pragma unroll
            for (int r = 0; r < 4; ++r) {
                int row = msub * 16 + kq * 4 + r;
                float pre = accA[t][r] + als[row] * accB[t][r] + cv;
                part[r] += leakyf(pre) * w2v;
            }
        }
    }
    #pragma unroll
    for (int r = 0; r < 4; ++r) {
        #pragma unroll
        for (int off = 1; off < 16; off <<= 1)
            part[r] += __shfl_xor(part[r], off, 64);
    }
    if (l15 == 0) {
        #pragma unroll
        for (int r = 0; r < 4; ++r)
            partial[msub * 16 + kq * 4 + r][half] = part[r];
    }
    __syncthreads();
    if (tid < 64) {
        int grow = row0 + tid;
        if (grow < N) {
            float s = partial[tid][0] + partial[tid][1] + pb2[0];
            out[grow] = 1.f / (1.f + expf(-s));
        }
    }
}

extern "C" void kernel_launch(void* const* d_in, const int* in_sizes, int n_in,
                              void* d_out, int out_size, void* d_ws, size_t ws_size,
                              hipStream_t stream)
{
    const int*   disc    = (const int*)d_in[0];
    const float* cont    = (const float*)d_in[1];
    const int*   eidx    = (const int*)d_in[2];
    const float* emb_W   = (const float*)d_in[5];
    const float* emb_b   = (const float*)d_in[6];
    const float* g0_W    = (const float*)d_in[7];
    const float* g0_b    = (const float*)d_in[8];
    const float* gcn1_W  = (const float*)d_in[9];
    const float* gcn1_b  = (const float*)d_in[10];
    const float* gcn2_W  = (const float*)d_in[11];
    const float* gcn2_b  = (const float*)d_in[12];
    const float* dnn_W1  = (const float*)d_in[13];
    const float* dnn_b1  = (const float*)d_in[14];
    const float* dnn_W2  = (const float*)d_in[15];
    const float* dnn_b2  = (const float*)d_in[16];
    const float* cross_w = (const float*)d_in[17];
    const float* cross_b = (const float*)d_in[18];
    const float* pred_W1 = (const float*)d_in[19];
    const float* pred_b1 = (const float*)d_in[20];
    const float* pred_W2 = (const float*)d_in[21];
    const float* pred_b2 = (const float*)d_in[22];

    const int N = in_sizes[0] / 38;
    const int E = in_sizes[2] / 2;
    const int* src = eidx;
    const int* dst = eidx + E;

    // ---- workspace (~117 MB @ N=1e5, E=1.6e6) ----
    float* xg   = (float*)d_ws;                       // [N,128] f32
    float* Z    = xg + (size_t)128 * N;               // [N,128] f32
    float* dis  = Z + (size_t)128 * N;                // [N]
    int* cnt    = (int*)(dis + N);                    // [N]
    int* rowp   = cnt + N;                            // [N]
    int* curs   = rowp + N;                           // [N] (incl -> cursor -> end)
    int* bsum   = curs + N;                           // [512]
    int2* colcf = (int2*)(((size_t)(bsum + 512) + 15) & ~(size_t)15);  // [E] {src,coeff}
    _Float16* wf = (_Float16*)(colcf + E);
    _Float16* G1f = wf;              // 4*8*512   = 16384
    _Float16* G2f = G1f + 16384;
    _Float16* W1f = G2f + 16384;     // 6*12*512  = 36864
    _Float16* W2f = W1f + 36864;
    _Float16* Paf = W2f + 36864;
    _Float16* Pbf = Paf + 36864;
    float* cvec   = (float*)(Pbf + 36864);            // [192]

    auto cdiv = [](int a, int b) { return (a + b - 1) / b; };
    const int nb = cdiv(N, 256);

    // weight prep (fragment-order fp16 planes)
    wsplit_frag<<<64, 256, 0, stream>>>(gcn1_W, 128, 128, 8, G1f, 16384);
    wsplit_frag<<<64, 256, 0, stream>>>(gcn2_W, 128, 128, 8, G2f, 16384);
    wsplit_frag<<<144, 256, 0, stream>>>(dnn_W1, 172, 172, 12, W1f, 36864);
    wsplit_frag<<<144, 256, 0, stream>>>(dnn_W2, 172, 172, 12, W2f, 36864);
    wsplit_frag<<<144, 256, 0, stream>>>(pred_W1, 172, 172, 12, Paf, 36864);
    wsplit_frag<<<144, 256, 0, stream>>>(pred_W1 + (size_t)172 * 172, 172, 172, 12, Pbf, 36864);
    cvec_kernel<<<1, 256, 0, stream>>>(pred_W1, cross_b, cross_w, cvec);

    // CSR build (+ per-edge coeff)
    hipMemsetAsync(cnt, 0, (size_t)N * sizeof(int), stream);
    cnt_edge_kernel<<<cdiv(E, 256), 256, 0, stream>>>(dst, cnt, E);
    dis_kernel<<<cdiv(N, 256), 256, 0, stream>>>(cnt, dis, N);
    scan1_kernel<<<nb, 256, 0, stream>>>(cnt, curs, bsum, N);
    scan2_kernel<<<1, 64, 0, stream>>>(bsum, nb);
    scan3_kernel<<<nb, 256, 0, stream>>>(curs, cnt, bsum, rowp, curs, N);
    fill_kernel<<<cdiv(E, 256), 256, 0, stream>>>(src, dst, dis, curs, colcf, E);

    // g0 -> xg
    g0_kernel<<<cdiv(N, 32), 256, 0, stream>>>(disc, cont, emb_W, emb_b, g0_W, g0_b, xg, N);

    // GCN layer 1 (agg first, then GEMM — linearity)
    agg_kernel<<<cdiv(N, 4), 256, 0, stream>>>(xg, colcf, rowp, curs, dis, Z, N);
    gcn_gemm<<<cdiv(N, 64), 256, 0, stream>>>(Z, G1f, gcn1_b, xg, N);
    // GCN layer 2
    agg_kernel<<<cdiv(N, 4), 256, 0, stream>>>(xg, colcf, rowp, curs, dis, Z, N);
    gcn_gemm<<<cdiv(N, 64), 256, 0, stream>>>(Z, G2f, gcn2_b, xg, N);

    // fused tail -> out
    tail_kernel<<<cdiv(N, 64), 512, 0, stream>>>(
        disc, cont, emb_W, emb_b, xg,
        W1f, dnn_b1, W2f, dnn_b2, Paf, Pbf, pred_b1,
        cross_w, cvec, pred_W2, pred_b2, (float*)d_out, N);
}

// Round 12
// 670.199 us; speedup vs baseline: 7.2179x; 1.0060x over previous
//
#include <hip/hip_runtime.h>
#include <math.h>

// ---------------------------------------------------------------------------
// DCN_89859305767621  Round 12:
//  - determinism fix: agg accumulates edge terms in scaled int64 (order-
//    independent sum) -> output bit-identical across replays regardless of
//    colcf atomic fill order (the replay-divergence root cause)
//  - otherwise identical to round 11 (round-7 numerics, no-spill tail)
// ---------------------------------------------------------------------------

typedef __attribute__((ext_vector_type(8))) _Float16 f16x8;
typedef __attribute__((ext_vector_type(4))) _Float16 f16x4;
typedef __attribute__((ext_vector_type(4))) float f32x4;

__device__ __forceinline__ float leakyf(float v) { return v > 0.f ? v : 0.01f * v; }

#define MFMA16(a, b, c) __builtin_amdgcn_mfma_f32_16x16x32_f16((a), (b), (c), 0, 0, 0)

// ---------------- CSR build ----------------
__global__ __launch_bounds__(256) void cnt_edge_kernel(const int* __restrict__ dst,
                                                       int* __restrict__ cnt, int E)
{
    int i = blockIdx.x * 256 + threadIdx.x;
    if (i < E) atomicAdd(&cnt[dst[i]], 1);
}

__global__ __launch_bounds__(256) void scan1_kernel(const int* __restrict__ cnt,
                                                    int* __restrict__ incl,
                                                    int* __restrict__ bsum, int N)
{
    __shared__ int s[256];
    int tid = threadIdx.x;
    int i = blockIdx.x * 256 + tid;
    s[tid] = (i < N) ? cnt[i] : 0;
    __syncthreads();
    #pragma unroll
    for (int off = 1; off < 256; off <<= 1) {
        int t = (tid >= off) ? s[tid - off] : 0;
        __syncthreads();
        s[tid] += t;
        __syncthreads();
    }
    if (i < N) incl[i] = s[tid];
    if (tid == 255) bsum[blockIdx.x] = s[255];
}

__global__ void scan2_kernel(int* __restrict__ bsum, int nb)   // 1 block, 64 threads
{
    int lane = threadIdx.x & 63;
    int run = 0;
    for (int base = 0; base < nb; base += 64) {
        int i = base + lane;
        int orig = (i < nb) ? bsum[i] : 0;
        int v = orig;
        #pragma unroll
        for (int off = 1; off < 64; off <<= 1) {
            int t = __shfl_up(v, off, 64);
            if (lane >= off) v += t;
        }
        if (i < nb) bsum[i] = run + v - orig;
        run += __shfl(v, 63, 64);
    }
}

__global__ __launch_bounds__(256) void scan3_kernel(const int* __restrict__ incl,
                                                    const int* __restrict__ cnt,
                                                    const int* __restrict__ bsum,
                                                    int* __restrict__ row_ptr,
                                                    int* __restrict__ cursor, int N)
{
    int i = blockIdx.x * 256 + threadIdx.x;
    if (i < N) {
        int v = incl[i] - cnt[i] + bsum[i >> 8];
        row_ptr[i] = v;
        cursor[i] = v;
    }
}

__global__ __launch_bounds__(256) void dis_kernel(const int* __restrict__ cnt,
                                                  float* __restrict__ dis, int N)
{
    int i = blockIdx.x * 256 + threadIdx.x;
    if (i < N) dis[i] = rsqrtf((float)cnt[i] + 1.0f);
}

// fill CSR adjacency with fused edge coefficient: colcf[p] = {src, dis_s*dis_d}
// (slot order within a row is atomic-order-dependent; consumers must be
//  order-independent — agg uses integer accumulation)
__global__ __launch_bounds__(256) void fill_kernel(const int* __restrict__ src,
                                                   const int* __restrict__ dst,
                                                   const float* __restrict__ dis,
                                                   int* __restrict__ cursor,
                                                   int2* __restrict__ colcf, int E)
{
    int e = blockIdx.x * 256 + threadIdx.x;
    if (e < E) {
        int s = src[e], d = dst[e];
        int p = atomicAdd(&cursor[d], 1);
        colcf[p] = make_int2(s, __float_as_int(dis[s] * dis[d]));
    }
}

// ---------------- weight prep: fragment-order fp16 plane (contiguous) -----
__global__ __launch_bounds__(256) void wsplit_frag(
    const float* __restrict__ W, int K, int Ncol, int NT,
    _Float16* __restrict__ Wf, int total)
{
    int idx = blockIdx.x * 256 + threadIdx.x;
    if (idx >= total) return;
    int e = idx & 7;
    int lane = (idx >> 3) & 63;
    int ct = idx >> 9;
    int t = ct % NT, c = ct / NT;
    int col = t * 16 + (lane & 15);
    int k = c * 32 + (lane >> 4) * 8 + e;
    float x = (k < K && col < Ncol) ? W[(size_t)k * Ncol + col] : 0.f;
    Wf[idx] = (_Float16)x;
}

// cvec[col] = sum_k (b1c[k]+b2c[k]) * PW1[172+k][col]; cvec[176] = dot(b1c, w2_cross)
__global__ __launch_bounds__(256) void cvec_kernel(
    const float* __restrict__ PW1, const float* __restrict__ cb,
    const float* __restrict__ cw, float* __restrict__ cvec)
{
    int col = threadIdx.x;
    if (col < 176) {
        float s = 0.f;
        if (col < 172)
            for (int k = 0; k < 172; ++k)
                s += (cb[k] + cb[172 + k]) * PW1[(size_t)(172 + k) * 172 + col];
        cvec[col] = s;
    } else if (col == 176) {
        float c = 0.f;
        for (int k = 0; k < 172; ++k) c += cb[k] * cw[172 + k];
        cvec[176] = c;
    }
}

// ---------------- g0: embed -> [N,44]@[44,128]+b, leaky -> xg f32 ---------
__global__ __launch_bounds__(256) void g0_kernel(
    const int* __restrict__ disc, const float* __restrict__ cont,
    const float* __restrict__ Wc, const float* __restrict__ bc,
    const float* __restrict__ W, const float* __restrict__ bias,
    float* __restrict__ xg, int N)
{
    constexpr int TM = 32, K = 44, RB = 8;
    __shared__ float Alds[TM][K];
    __shared__ float Wlds[K][128];
    const int tid = threadIdx.x, lane = tid & 63, wv = tid >> 6;
    const int row0 = blockIdx.x * TM;

    for (int idx = tid; idx < TM * 38; idx += 256) {
        int r = idx / 38, j = idx - r * 38;
        int row = row0 + r;
        if (j == 0) {
            float o = 0.f;
            if (row < N) {
                const int* dr = disc + (size_t)row * 38;
                int best = dr[0], bi = 0;
                #pragma unroll
                for (int q = 1; q < 7; ++q) { int v = dr[q]; if (v > best) { best = v; bi = q; } }
                o = (float)bi;
            }
            Alds[r][0] = o;
        } else if (j >= 7) {
            Alds[r][j - 6] = (row < N) ? (float)disc[(size_t)row * 38 + j] : 0.f;
        }
    }
    for (int idx = tid; idx < TM * 12; idx += 256) {
        int r = idx / 12, q = idx - r * 12;
        int t = q >> 2, ch = q & 3;
        int row = row0 + r;
        float s = 0.f;
        if (row < N) {
            s = bc[ch];
            const float* cr = cont + (size_t)row * 90 + t * 30;
            #pragma unroll
            for (int j = 0; j < 30; ++j) s += cr[j] * Wc[j * 4 + ch];
        }
        Alds[r][32 + t * 4 + ch] = s;
    }
    for (int idx = tid; idx < K * 32; idx += 256) {
        int k = idx >> 5, c4 = idx & 31;
        ((float4*)&Wlds[k][0])[c4] = ((const float4*)W)[idx];
    }
    __syncthreads();

    float acc[RB][2];
    float b0 = bias[lane], b1 = bias[lane + 64];
    #pragma unroll
    for (int r = 0; r < RB; ++r) { acc[r][0] = b0; acc[r][1] = b1; }

    for (int k = 0; k < K; ++k) {
        float w0 = Wlds[k][lane], w1 = Wlds[k][lane + 64];
        #pragma unroll
        for (int r = 0; r < RB; ++r) {
            float a = Alds[wv * RB + r][k];
            acc[r][0] += a * w0;
            acc[r][1] += a * w1;
        }
    }
    #pragma unroll
    for (int r = 0; r < RB; ++r) {
        int row = row0 + wv * RB + r;
        if (row < N) {
            xg[(size_t)row * 128 + lane]      = leakyf(acc[r][0]);
            xg[(size_t)row * 128 + lane + 64] = leakyf(acc[r][1]);
        }
    }
}

// ---------------- agg: Z = D^-1/2 (A+I) D^-1/2 xg -------------------------
// Edge terms accumulated in scaled int64: integer addition is associative,
// so the row sum is independent of colcf slot order -> bit-deterministic.
#define AGG_SCALE 1048576.0f   // 2^20
#define AGG_INV   9.5367431640625e-07f
__global__ __launch_bounds__(256) void agg_kernel(
    const float* __restrict__ xg, const int2* __restrict__ colcf,
    const int* __restrict__ rowp, const int* __restrict__ rend,
    const float* __restrict__ dis, float* __restrict__ Z, int N)
{
    int gw = (int)(((size_t)blockIdx.x * 256 + threadIdx.x) >> 6);
    int lane = threadIdx.x & 63;
    if (gw >= N) return;
    const float2* X2 = (const float2*)xg;
    int i = rowp[gw], en = rend[gw];
    long long iax = 0, iay = 0;
    for (; i + 3 < en; i += 4) {
        int2 e0 = colcf[i],     e1 = colcf[i + 1];
        int2 e2 = colcf[i + 2], e3 = colcf[i + 3];
        float2 v0 = X2[(size_t)e0.x * 64 + lane];
        float2 v1 = X2[(size_t)e1.x * 64 + lane];
        float2 v2 = X2[(size_t)e2.x * 64 + lane];
        float2 v3 = X2[(size_t)e3.x * 64 + lane];
        float c0 = __int_as_float(e0.y) * AGG_SCALE;
        float c1 = __int_as_float(e1.y) * AGG_SCALE;
        float c2 = __int_as_float(e2.y) * AGG_SCALE;
        float c3 = __int_as_float(e3.y) * AGG_SCALE;
        iax += __float2int_rn(v0.x * c0); iay += __float2int_rn(v0.y * c0);
        iax += __float2int_rn(v1.x * c1); iay += __float2int_rn(v1.y * c1);
        iax += __float2int_rn(v2.x * c2); iay += __float2int_rn(v2.y * c2);
        iax += __float2int_rn(v3.x * c3); iay += __float2int_rn(v3.y * c3);
    }
    for (; i < en; ++i) {
        int2 e = colcf[i];
        float2 v = X2[(size_t)e.x * 64 + lane];
        float cf = __int_as_float(e.y) * AGG_SCALE;
        iax += __float2int_rn(v.x * cf);
        iay += __float2int_rn(v.y * cf);
    }
    float ax = (float)iax * AGG_INV;
    float ay = (float)iay * AGG_INV;
    float dn = dis[gw];
    float2 sv = X2[(size_t)gw * 64 + lane];
    float d2 = dn * dn;
    float2 o;
    o.x = ax + sv.x * d2;
    o.y = ay + sv.y * d2;
    ((float2*)Z)[(size_t)gw * 64 + lane] = o;
}

// ---------------- gcn GEMM: xg = leaky(Z @ G + b), fp16 MFMA --------------
__global__ __launch_bounds__(256, 4) void gcn_gemm(
    const float* __restrict__ Z, const _Float16* __restrict__ B,
    const float* __restrict__ bias, float* __restrict__ xg, int N)
{
    __shared__ __attribute__((aligned(16))) _Float16 Xs[64][136];
    const int tid = threadIdx.x, lane = tid & 63, msub = tid >> 6;
    const int l15 = lane & 15, kq = lane >> 4;
    const int row0 = blockIdx.x * 64;

    for (int idx = tid; idx < 2048; idx += 256) {
        int r = idx >> 5, q = idx & 31;
        int row = row0 + r;
        float4 v = make_float4(0.f, 0.f, 0.f, 0.f);
        if (row < N) v = *(const float4*)(Z + (size_t)row * 128 + q * 4);
        f16x4 h = { (_Float16)v.x, (_Float16)v.y, (_Float16)v.z, (_Float16)v.w };
        *(f16x4*)&Xs[r][q * 4] = h;
    }
    __syncthreads();

    f32x4 acc[8];
    #pragma unroll
    for (int t = 0; t < 8; ++t) acc[t] = (f32x4){0.f, 0.f, 0.f, 0.f};

    #pragma unroll
    for (int c = 0; c < 4; ++c) {
        f16x8 a = *(const f16x8*)&Xs[msub * 16 + l15][c * 32 + kq * 8];
        #pragma unroll
        for (int t = 0; t < 8; ++t) {
            f16x8 b = *(const f16x8*)(B + (((size_t)c * 8 + t) * 64 + lane) * 8);
            acc[t] = MFMA16(a, b, acc[t]);
        }
    }

    #pragma unroll
    for (int t = 0; t < 8; ++t) {
        int col = t * 16 + l15;
        float bb = bias[col];
        #pragma unroll
        for (int r = 0; r < 4; ++r) {
            int row = row0 + msub * 16 + kq * 4 + r;
            if (row < N)
                xg[(size_t)row * 128 + col] = leakyf(acc[t][r] + bb);
        }
    }
}

// ---------------- tail helpers (contiguous layout, embed recompute) -------
__device__ __forceinline__ void stage_x16(
    const int* __restrict__ disc, const float* __restrict__ cont,
    const float* __restrict__ Wc, const float* __restrict__ bc,
    const float* __restrict__ xg, _Float16 (*Xs)[200], int row0, int N, int tid)
{
    for (int idx = tid; idx < 64 * 44; idx += 512) {
        int r = idx / 44, j = idx - r * 44;
        int row = row0 + r;
        float v = 0.f;
        if (row < N) {
            if (j == 0) {
                const int* dr = disc + (size_t)row * 38;
                int best = dr[0], bi = 0;
                #pragma unroll
                for (int q = 1; q < 7; ++q) { int t = dr[q]; if (t > best) { best = t; bi = q; } }
                v = (float)bi;
            } else if (j < 32) {
                v = (float)disc[(size_t)row * 38 + j + 6];
            } else {
                int q = j - 32, t = q >> 2, ch = q & 3;
                float s = bc[ch];
                const float* cr = cont + (size_t)row * 90 + t * 30;
                #pragma unroll
                for (int kk = 0; kk < 30; ++kk) s += cr[kk] * Wc[kk * 4 + ch];
                v = s;
            }
        }
        Xs[r][j] = (_Float16)v;
    }
    for (int idx = tid; idx < 2048; idx += 512) {
        int r = idx >> 5, q = idx & 31;
        int row = row0 + r;
        float4 v = make_float4(0.f, 0.f, 0.f, 0.f);
        if (row < N) v = *(const float4*)(xg + (size_t)row * 128 + q * 4);
        f16x4 h = { (_Float16)v.x, (_Float16)v.y, (_Float16)v.z, (_Float16)v.w };
        *(f16x4*)&Xs[r][44 + q * 4] = h;
    }
    for (int idx = tid; idx < 64 * 28; idx += 512) {
        int r = idx / 28, j = idx - r * 28;
        Xs[r][172 + j] = (_Float16)0.f;
    }
}

// one pass: 6 K-chunks x 6 N-tiles per wave (cols half*96 + t*16 + l15),
// B-fragments loaded directly from L2 (no register prefetch arrays)
__device__ __forceinline__ void gemm_pass6(
    const _Float16 (*X)[200], const _Float16* __restrict__ B,
    f32x4* acc, int msub, int half, int l15, int kq, int lane)
{
    #pragma unroll
    for (int t = 0; t < 6; ++t) acc[t] = (f32x4){0.f, 0.f, 0.f, 0.f};
    #pragma unroll
    for (int c = 0; c < 6; ++c) {
        f16x8 a = *(const f16x8*)&X[msub * 16 + l15][c * 32 + kq * 8];
        #pragma unroll
        for (int t = 0; t < 6; ++t) {
            f16x8 b = *(const f16x8*)(B + (((size_t)c * 12 + half * 6 + t) * 64 + lane) * 8);
            acc[t] = MFMA16(a, b, acc[t]);
        }
    }
}

// ---------------- fused tail: dnn1+dnn2+pred1(a,b)+cross+pred2+sigmoid ----
__global__ __launch_bounds__(512, 3) void tail_kernel(
    const int* __restrict__ disc, const float* __restrict__ cont,
    const float* __restrict__ Wc, const float* __restrict__ bc,
    const float* __restrict__ xg,
    const _Float16* __restrict__ W1, const float* __restrict__ b1,
    const _Float16* __restrict__ W2, const float* __restrict__ b2,
    const _Float16* __restrict__ Pa, const _Float16* __restrict__ Pb,
    const float* __restrict__ pb1,
    const float* __restrict__ cw, const float* __restrict__ cvec,
    const float* __restrict__ pw2, const float* __restrict__ pb2,
    float* __restrict__ out, int N)
{
    __shared__ __attribute__((aligned(16))) _Float16 Xs[64][200];
    __shared__ __attribute__((aligned(16))) _Float16 Ts[64][200];
    __shared__ float als[64];
    __shared__ float partial[64][2];
    const int tid = threadIdx.x, lane = tid & 63, wv = tid >> 6;
    const int msub = wv >> 1, half = wv & 1, l15 = lane & 15, kq = lane >> 4;
    const int row0 = blockIdx.x * 64;

    stage_x16(disc, cont, Wc, bc, xg, Xs, row0, N, tid);
    __syncthreads();

    // per-row cross scalars: xl2 = als*x0 + (b1c+b2c)
    {
        int row = tid >> 3, sub = tid & 7;
        float d1 = 0.f, d2 = 0.f;
        for (int col = sub; col < 172; col += 8) {
            float x = (float)Xs[row][col];
            d1 += x * cw[col];
            d2 += x * cw[172 + col];
        }
        #pragma unroll
        for (int off = 1; off < 8; off <<= 1) {
            d1 += __shfl_xor(d1, off, 64);
            d2 += __shfl_xor(d2, off, 64);
        }
        if (sub == 0) {
            float a1 = 1.f + d1;
            als[row] = a1 + a1 * d2 + cvec[176];
        }
    }

    f32x4 accA[6], accB[6];

    // dnn1: Xs -> Ts
    gemm_pass6(Xs, W1, accA, msub, half, l15, kq, lane);
    #pragma unroll
    for (int t = 0; t < 6; ++t) {
        int col = half * 96 + t * 16 + l15;
        #pragma unroll
        for (int r = 0; r < 4; ++r) {
            int row = msub * 16 + kq * 4 + r;
            float v = (col < 172) ? leakyf(accA[t][r] + b1[col]) : 0.f;
            Ts[row][col] = (_Float16)v;
        }
    }
    __syncthreads();
    // dnn2: Ts -> Ts (in place)
    gemm_pass6(Ts, W2, accA, msub, half, l15, kq, lane);
    __syncthreads();
    #pragma unroll
    for (int t = 0; t < 6; ++t) {
        int col = half * 96 + t * 16 + l15;
        #pragma unroll
        for (int r = 0; r < 4; ++r) {
            int row = msub * 16 + kq * 4 + r;
            float v = (col < 172) ? leakyf(accA[t][r] + b2[col]) : 0.f;
            Ts[row][col] = (_Float16)v;
        }
    }
    __syncthreads();

    // pred1: accA = xdeep@Pa (from Ts), accB = x0@Pb (from Xs)
    gemm_pass6(Ts, Pa, accA, msub, half, l15, kq, lane);
    gemm_pass6(Xs, Pb, accB, msub, half, l15, kq, lane);

    // epilogue: pre = accA + pb1 + als*accB + cvec -> leaky -> . pw2 -> sigmoid
    float part[4] = {0.f, 0.f, 0.f, 0.f};
    #pragma unroll
    for (int t = 0; t < 6; ++t) {
        int col = half * 96 + t * 16 + l15;
        if (col < 172) {
            float cv = cvec[col] + pb1[col], w2v = pw2[col];
            #pragma unroll
            for (int r = 0; r < 4; ++r) {
                int row = msub * 16 + kq * 4 + r;
                float pre = accA[t][r] + als[row] * accB[t][r] + cv;
                part[r] += leakyf(pre) * w2v;
            }
        }
    }
    #pragma unroll
    for (int r = 0; r < 4; ++r) {
        #pragma unroll
        for (int off = 1; off < 16; off <<= 1)
            part[r] += __shfl_xor(part[r], off, 64);
    }
    if (l15 == 0) {
        #pragma unroll
        for (int r = 0; r < 4; ++r)
            partial[msub * 16 + kq * 4 + r][half] = part[r];
    }
    __syncthreads();
    if (tid < 64) {
        int grow = row0 + tid;
        if (grow < N) {
            float s = partial[tid][0] + partial[tid][1] + pb2[0];
            out[grow] = 1.f / (1.f + expf(-s));
        }
    }
}

extern "C" void kernel_launch(void* const* d_in, const int* in_sizes, int n_in,
                              void* d_out, int out_size, void* d_ws, size_t ws_size,
                              hipStream_t stream)
{
    const int*   disc    = (const int*)d_in[0];
    const float* cont    = (const float*)d_in[1];
    const int*   eidx    = (const int*)d_in[2];
    const float* emb_W   = (const float*)d_in[5];
    const float* emb_b   = (const float*)d_in[6];
    const float* g0_W    = (const float*)d_in[7];
    const float* g0_b    = (const float*)d_in[8];
    const float* gcn1_W  = (const float*)d_in[9];
    const float* gcn1_b  = (const float*)d_in[10];
    const float* gcn2_W  = (const float*)d_in[11];
    const float* gcn2_b  = (const float*)d_in[12];
    const float* dnn_W1  = (const float*)d_in[13];
    const float* dnn_b1  = (const float*)d_in[14];
    const float* dnn_W2  = (const float*)d_in[15];
    const float* dnn_b2  = (const float*)d_in[16];
    const float* cross_w = (const float*)d_in[17];
    const float* cross_b = (const float*)d_in[18];
    const float* pred_W1 = (const float*)d_in[19];
    const float* pred_b1 = (const float*)d_in[20];
    const float* pred_W2 = (const float*)d_in[21];
    const float* pred_b2 = (const float*)d_in[22];

    const int N = in_sizes[0] / 38;
    const int E = in_sizes[2] / 2;
    const int* src = eidx;
    const int* dst = eidx + E;

    // ---- workspace (~117 MB @ N=1e5, E=1.6e6 — round-7 proven layout) ----
    float* xg   = (float*)d_ws;                       // [N,128] f32
    float* Z    = xg + (size_t)128 * N;               // [N,128] f32
    float* dis  = Z + (size_t)128 * N;                // [N]
    int* cnt    = (int*)(dis + N);                    // [N]
    int* rowp   = cnt + N;                            // [N]
    int* curs   = rowp + N;                           // [N] (incl -> cursor -> end)
    int* bsum   = curs + N;                           // [512]
    int2* colcf = (int2*)(((size_t)(bsum + 512) + 15) & ~(size_t)15);  // [E] {src,coeff}
    _Float16* wf = (_Float16*)(colcf + E);
    _Float16* G1f = wf;              // 4*8*512   = 16384
    _Float16* G2f = G1f + 16384;
    _Float16* W1f = G2f + 16384;     // 6*12*512  = 36864
    _Float16* W2f = W1f + 36864;
    _Float16* Paf = W2f + 36864;
    _Float16* Pbf = Paf + 36864;
    float* cvec   = (float*)(Pbf + 36864);            // [192]

    auto cdiv = [](int a, int b) { return (a + b - 1) / b; };
    const int nb = cdiv(N, 256);

    // weight prep (fragment-order fp16 planes)
    wsplit_frag<<<64, 256, 0, stream>>>(gcn1_W, 128, 128, 8, G1f, 16384);
    wsplit_frag<<<64, 256, 0, stream>>>(gcn2_W, 128, 128, 8, G2f, 16384);
    wsplit_frag<<<144, 256, 0, stream>>>(dnn_W1, 172, 172, 12, W1f, 36864);
    wsplit_frag<<<144, 256, 0, stream>>>(dnn_W2, 172, 172, 12, W2f, 36864);
    wsplit_frag<<<144, 256, 0, stream>>>(pred_W1, 172, 172, 12, Paf, 36864);
    wsplit_frag<<<144, 256, 0, stream>>>(pred_W1 + (size_t)172 * 172, 172, 172, 12, Pbf, 36864);
    cvec_kernel<<<1, 256, 0, stream>>>(pred_W1, cross_b, cross_w, cvec);

    // CSR build (+ per-edge coeff)
    hipMemsetAsync(cnt, 0, (size_t)N * sizeof(int), stream);
    cnt_edge_kernel<<<cdiv(E, 256), 256, 0, stream>>>(dst, cnt, E);
    dis_kernel<<<cdiv(N, 256), 256, 0, stream>>>(cnt, dis, N);
    scan1_kernel<<<nb, 256, 0, stream>>>(cnt, curs, bsum, N);
    scan2_kernel<<<1, 64, 0, stream>>>(bsum, nb);
    scan3_kernel<<<nb, 256, 0, stream>>>(curs, cnt, bsum, rowp, curs, N);
    fill_kernel<<<cdiv(E, 256), 256, 0, stream>>>(src, dst, dis, curs, colcf, E);

    // g0 -> xg
    g0_kernel<<<cdiv(N, 32), 256, 0, stream>>>(disc, cont, emb_W, emb_b, g0_W, g0_b, xg, N);

    // GCN layer 1 (agg first, then GEMM — linearity)
    agg_kernel<<<cdiv(N, 4), 256, 0, stream>>>(xg, colcf, rowp, curs, dis, Z, N);
    gcn_gemm<<<cdiv(N, 64), 256, 0, stream>>>(Z, G1f, gcn1_b, xg, N);
    // GCN layer 2
    agg_kernel<<<cdiv(N, 4), 256, 0, stream>>>(xg, colcf, rowp, curs, dis, Z, N);
    gcn_gemm<<<cdiv(N, 64), 256, 0, stream>>>(Z, G2f, gcn2_b, xg, N);

    // fused tail -> out
    tail_kernel<<<cdiv(N, 64), 512, 0, stream>>>(
        disc, cont, emb_W, emb_b, xg,
        W1f, dnn_b1, W2f, dnn_b2, Paf, Pbf, pred_b1,
        cross_w, cvec, pred_W2, pred_b2, (float*)d_out, N);
}

// Round 13
// 639.943 us; speedup vs baseline: 7.5592x; 1.0473x over previous
//
#include <hip/hip_runtime.h>
#include <math.h>

// ---------------------------------------------------------------------------
// DCN_89859305767621  Round 13:
//  - fuse agg + gcn_gemm (Z round-trip eliminated, ~102 MB/layer saved);
//    gather uses the int64 order-independent sum (determinism preserved),
//    f16 only at LDS staging -> MFMA inputs bit-identical to round 12
//  - weight prep collapsed to 1 launch; dis folded into scan3 (20 -> 11)
//  - tail unchanged (proven at 3.9e-3)
// ---------------------------------------------------------------------------

typedef __attribute__((ext_vector_type(8))) _Float16 f16x8;
typedef __attribute__((ext_vector_type(4))) _Float16 f16x4;
typedef __attribute__((ext_vector_type(2))) _Float16 f16x2;
typedef __attribute__((ext_vector_type(4))) float f32x4;

__device__ __forceinline__ float leakyf(float v) { return v > 0.f ? v : 0.01f * v; }

#define MFMA16(a, b, c) __builtin_amdgcn_mfma_f32_16x16x32_f16((a), (b), (c), 0, 0, 0)
#define AGG_SCALE 1048576.0f   // 2^20
#define AGG_INV   9.5367431640625e-07f

// ---------------- CSR build ----------------
__global__ __launch_bounds__(256) void cnt_edge_kernel(const int* __restrict__ dst,
                                                       int* __restrict__ cnt, int E)
{
    int i = blockIdx.x * 256 + threadIdx.x;
    if (i < E) atomicAdd(&cnt[dst[i]], 1);
}

__global__ __launch_bounds__(256) void scan1_kernel(const int* __restrict__ cnt,
                                                    int* __restrict__ incl,
                                                    int* __restrict__ bsum, int N)
{
    __shared__ int s[256];
    int tid = threadIdx.x;
    int i = blockIdx.x * 256 + tid;
    s[tid] = (i < N) ? cnt[i] : 0;
    __syncthreads();
    #pragma unroll
    for (int off = 1; off < 256; off <<= 1) {
        int t = (tid >= off) ? s[tid - off] : 0;
        __syncthreads();
        s[tid] += t;
        __syncthreads();
    }
    if (i < N) incl[i] = s[tid];
    if (tid == 255) bsum[blockIdx.x] = s[255];
}

__global__ void scan2_kernel(int* __restrict__ bsum, int nb)   // 1 block, 64 threads
{
    int lane = threadIdx.x & 63;
    int run = 0;
    for (int base = 0; base < nb; base += 64) {
        int i = base + lane;
        int orig = (i < nb) ? bsum[i] : 0;
        int v = orig;
        #pragma unroll
        for (int off = 1; off < 64; off <<= 1) {
            int t = __shfl_up(v, off, 64);
            if (lane >= off) v += t;
        }
        if (i < nb) bsum[i] = run + v - orig;
        run += __shfl(v, 63, 64);
    }
}

// row_ptr/cursor + dis = rsqrt(deg+1)   (dis folded in; runs before fill)
__global__ __launch_bounds__(256) void scan3_kernel(const int* __restrict__ incl,
                                                    const int* __restrict__ cnt,
                                                    const int* __restrict__ bsum,
                                                    int* __restrict__ row_ptr,
                                                    int* __restrict__ cursor,
                                                    float* __restrict__ dis, int N)
{
    int i = blockIdx.x * 256 + threadIdx.x;
    if (i < N) {
        int v = incl[i] - cnt[i] + bsum[i >> 8];
        row_ptr[i] = v;
        cursor[i] = v;
        dis[i] = rsqrtf((float)cnt[i] + 1.0f);
    }
}

// fill CSR adjacency with fused edge coefficient: colcf[p] = {src, dis_s*dis_d}
// (slot order is atomic-order-dependent; consumer uses order-independent sum)
__global__ __launch_bounds__(256) void fill_kernel(const int* __restrict__ src,
                                                   const int* __restrict__ dst,
                                                   const float* __restrict__ dis,
                                                   int* __restrict__ cursor,
                                                   int2* __restrict__ colcf, int E)
{
    int e = blockIdx.x * 256 + threadIdx.x;
    if (e < E) {
        int s = src[e], d = dst[e];
        int p = atomicAdd(&cursor[d], 1);
        colcf[p] = make_int2(s, __float_as_int(dis[s] * dis[d]));
    }
}

// ---------------- weight prep: all 6 fp16 fragment planes + cvec, 1 launch --
// frag layout: idx = ((c*NT + t)*64 + lane)*8 + e ; col = t*16+(lane&15) ;
// k = c*32+(lane>>4)*8+e ; zero-padded outside K x Ncol
__global__ __launch_bounds__(256) void wprep_kernel(
    const float* __restrict__ gcn1_W, const float* __restrict__ gcn2_W,
    const float* __restrict__ dnn_W1, const float* __restrict__ dnn_W2,
    const float* __restrict__ pred_W1,
    const float* __restrict__ cb, const float* __restrict__ cw,
    _Float16* __restrict__ G1f, _Float16* __restrict__ G2f,
    _Float16* __restrict__ W1f, _Float16* __restrict__ W2f,
    _Float16* __restrict__ Paf, _Float16* __restrict__ Pbf,
    float* __restrict__ cvec)
{
    int b = blockIdx.x;
    if (b == 704) {   // cvec: col sums + cross scalar constant
        int col = threadIdx.x;
        if (col < 176) {
            float s = 0.f;
            if (col < 172)
                for (int k = 0; k < 172; ++k)
                    s += (cb[k] + cb[172 + k]) * pred_W1[(size_t)(172 + k) * 172 + col];
            cvec[col] = s;
        } else if (col == 176) {
            float c = 0.f;
            for (int k = 0; k < 172; ++k) c += cb[k] * cw[172 + k];
            cvec[176] = c;
        }
        return;
    }
    const float* W; _Float16* Wf; int K, Ncol, NT, base;
    if (b < 64)       { W = gcn1_W; Wf = G1f; K = 128; Ncol = 128; NT = 8;  base = 0;   }
    else if (b < 128) { W = gcn2_W; Wf = G2f; K = 128; Ncol = 128; NT = 8;  base = 64;  }
    else if (b < 272) { W = dnn_W1; Wf = W1f; K = 172; Ncol = 172; NT = 12; base = 128; }
    else if (b < 416) { W = dnn_W2; Wf = W2f; K = 172; Ncol = 172; NT = 12; base = 272; }
    else if (b < 560) { W = pred_W1; Wf = Paf; K = 172; Ncol = 172; NT = 12; base = 416; }
    else              { W = pred_W1 + (size_t)172 * 172; Wf = Pbf; K = 172; Ncol = 172; NT = 12; base = 560; }
    int idx = (b - base) * 256 + threadIdx.x;
    int e = idx & 7;
    int lane = (idx >> 3) & 63;
    int ct = idx >> 9;
    int t = ct % NT, c = ct / NT;
    int col = t * 16 + (lane & 15);
    int k = c * 32 + (lane >> 4) * 8 + e;
    float x = (k < K && col < Ncol) ? W[(size_t)k * Ncol + col] : 0.f;
    Wf[idx] = (_Float16)x;
}

// ---------------- g0: embed -> [N,44]@[44,128]+b, leaky -> xg f32 ---------
__global__ __launch_bounds__(256) void g0_kernel(
    const int* __restrict__ disc, const float* __restrict__ cont,
    const float* __restrict__ Wc, const float* __restrict__ bc,
    const float* __restrict__ W, const float* __restrict__ bias,
    float* __restrict__ xg, int N)
{
    constexpr int TM = 32, K = 44, RB = 8;
    __shared__ float Alds[TM][K];
    __shared__ float Wlds[K][128];
    const int tid = threadIdx.x, lane = tid & 63, wv = tid >> 6;
    const int row0 = blockIdx.x * TM;

    for (int idx = tid; idx < TM * 38; idx += 256) {
        int r = idx / 38, j = idx - r * 38;
        int row = row0 + r;
        if (j == 0) {
            float o = 0.f;
            if (row < N) {
                const int* dr = disc + (size_t)row * 38;
                int best = dr[0], bi = 0;
                #pragma unroll
                for (int q = 1; q < 7; ++q) { int v = dr[q]; if (v > best) { best = v; bi = q; } }
                o = (float)bi;
            }
            Alds[r][0] = o;
        } else if (j >= 7) {
            Alds[r][j - 6] = (row < N) ? (float)disc[(size_t)row * 38 + j] : 0.f;
        }
    }
    for (int idx = tid; idx < TM * 12; idx += 256) {
        int r = idx / 12, q = idx - r * 12;
        int t = q >> 2, ch = q & 3;
        int row = row0 + r;
        float s = 0.f;
        if (row < N) {
            s = bc[ch];
            const float* cr = cont + (size_t)row * 90 + t * 30;
            #pragma unroll
            for (int j = 0; j < 30; ++j) s += cr[j] * Wc[j * 4 + ch];
        }
        Alds[r][32 + t * 4 + ch] = s;
    }
    for (int idx = tid; idx < K * 32; idx += 256) {
        int k = idx >> 5, c4 = idx & 31;
        ((float4*)&Wlds[k][0])[c4] = ((const float4*)W)[idx];
    }
    __syncthreads();

    float acc[RB][2];
    float b0 = bias[lane], b1 = bias[lane + 64];
    #pragma unroll
    for (int r = 0; r < RB; ++r) { acc[r][0] = b0; acc[r][1] = b1; }

    for (int k = 0; k < K; ++k) {
        float w0 = Wlds[k][lane], w1 = Wlds[k][lane + 64];
        #pragma unroll
        for (int r = 0; r < RB; ++r) {
            float a = Alds[wv * RB + r][k];
            acc[r][0] += a * w0;
            acc[r][1] += a * w1;
        }
    }
    #pragma unroll
    for (int r = 0; r < RB; ++r) {
        int row = row0 + wv * RB + r;
        if (row < N) {
            xg[(size_t)row * 128 + lane]      = leakyf(acc[r][0]);
            xg[(size_t)row * 128 + lane + 64] = leakyf(acc[r][1]);
        }
    }
}

// ---------------- fused GCN layer: xout = leaky(AGG(xin) @ G + b) ----------
// Phase 1: wave wv gathers+combines rows row0+wv*8..+7 (int64 deterministic
//          sum), stages result as f16 into LDS (same rounding point as the
//          old Z->staging path -> bit-identical MFMA inputs).
// Phase 2: 8-wave MFMA GEMM + bias + leaky -> xout f32.
__global__ __launch_bounds__(512, 4) void gcn_fused(
    const float* __restrict__ xin, const int2* __restrict__ colcf,
    const int* __restrict__ rowp, const int* __restrict__ rend,
    const float* __restrict__ dis, const _Float16* __restrict__ B,
    const float* __restrict__ bias, float* __restrict__ xout, int N)
{
    __shared__ __attribute__((aligned(16))) _Float16 Xs[64][136];
    const int tid = threadIdx.x, lane = tid & 63, wv = tid >> 6;
    const int l15 = lane & 15, kq = lane >> 4;
    const int row0 = blockIdx.x * 64;
    const float2* X2 = (const float2*)xin;

    // ---- phase 1: gather + self-loop
    #pragma unroll 1
    for (int rr = 0; rr < 8; ++rr) {
        const int r = (wv << 3) + rr;
        const int row = row0 + r;
        float ox = 0.f, oy = 0.f;
        if (row < N) {
            int i = rowp[row], en = rend[row];
            long long iax = 0, iay = 0;
            for (; i + 3 < en; i += 4) {
                int2 e0 = colcf[i],     e1 = colcf[i + 1];
                int2 e2 = colcf[i + 2], e3 = colcf[i + 3];
                float2 v0 = X2[(size_t)e0.x * 64 + lane];
                float2 v1 = X2[(size_t)e1.x * 64 + lane];
                float2 v2 = X2[(size_t)e2.x * 64 + lane];
                float2 v3 = X2[(size_t)e3.x * 64 + lane];
                float c0 = __int_as_float(e0.y) * AGG_SCALE;
                float c1 = __int_as_float(e1.y) * AGG_SCALE;
                float c2 = __int_as_float(e2.y) * AGG_SCALE;
                float c3 = __int_as_float(e3.y) * AGG_SCALE;
                iax += __float2int_rn(v0.x * c0); iay += __float2int_rn(v0.y * c0);
                iax += __float2int_rn(v1.x * c1); iay += __float2int_rn(v1.y * c1);
                iax += __float2int_rn(v2.x * c2); iay += __float2int_rn(v2.y * c2);
                iax += __float2int_rn(v3.x * c3); iay += __float2int_rn(v3.y * c3);
            }
            for (; i < en; ++i) {
                int2 e = colcf[i];
                float2 v = X2[(size_t)e.x * 64 + lane];
                float cf = __int_as_float(e.y) * AGG_SCALE;
                iax += __float2int_rn(v.x * cf);
                iay += __float2int_rn(v.y * cf);
            }
            float ax = (float)iax * AGG_INV;
            float ay = (float)iay * AGG_INV;
            float dn = dis[row];
            float2 sv = X2[(size_t)row * 64 + lane];
            float d2 = dn * dn;
            ox = ax + sv.x * d2;
            oy = ay + sv.y * d2;
        }
        f16x2 h = { (_Float16)ox, (_Float16)oy };
        *(f16x2*)&Xs[r][lane * 2] = h;
    }
    __syncthreads();

    // ---- phase 2: GEMM (wave = msub x half; 4 col-tiles per wave)
    const int msub = wv >> 1, half = wv & 1;
    f32x4 acc[4];
    #pragma unroll
    for (int t = 0; t < 4; ++t) acc[t] = (f32x4){0.f, 0.f, 0.f, 0.f};

    #pragma unroll
    for (int c = 0; c < 4; ++c) {
        f16x8 a = *(const f16x8*)&Xs[msub * 16 + l15][c * 32 + kq * 8];
        #pragma unroll
        for (int t = 0; t < 4; ++t) {
            int tg = half * 4 + t;
            f16x8 b = *(const f16x8*)(B + (((size_t)c * 8 + tg) * 64 + lane) * 8);
            acc[t] = MFMA16(a, b, acc[t]);
        }
    }

    #pragma unroll
    for (int t = 0; t < 4; ++t) {
        int col = (half * 4 + t) * 16 + l15;
        float bb = bias[col];
        #pragma unroll
        for (int r = 0; r < 4; ++r) {
            int row = row0 + msub * 16 + kq * 4 + r;
            if (row < N)
                xout[(size_t)row * 128 + col] = leakyf(acc[t][r] + bb);
        }
    }
}

// ---------------- tail helpers (contiguous layout, embed recompute) -------
__device__ __forceinline__ void stage_x16(
    const int* __restrict__ disc, const float* __restrict__ cont,
    const float* __restrict__ Wc, const float* __restrict__ bc,
    const float* __restrict__ xg, _Float16 (*Xs)[200], int row0, int N, int tid)
{
    for (int idx = tid; idx < 64 * 44; idx += 512) {
        int r = idx / 44, j = idx - r * 44;
        int row = row0 + r;
        float v = 0.f;
        if (row < N) {
            if (j == 0) {
                const int* dr = disc + (size_t)row * 38;
                int best = dr[0], bi = 0;
                #pragma unroll
                for (int q = 1; q < 7; ++q) { int t = dr[q]; if (t > best) { best = t; bi = q; } }
                v = (float)bi;
            } else if (j < 32) {
                v = (float)disc[(size_t)row * 38 + j + 6];
            } else {
                int q = j - 32, t = q >> 2, ch = q & 3;
                float s = bc[ch];
                const float* cr = cont + (size_t)row * 90 + t * 30;
                #pragma unroll
                for (int kk = 0; kk < 30; ++kk) s += cr[kk] * Wc[kk * 4 + ch];
                v = s;
            }
        }
        Xs[r][j] = (_Float16)v;
    }
    for (int idx = tid; idx < 2048; idx += 512) {
        int r = idx >> 5, q = idx & 31;
        int row = row0 + r;
        float4 v = make_float4(0.f, 0.f, 0.f, 0.f);
        if (row < N) v = *(const float4*)(xg + (size_t)row * 128 + q * 4);
        f16x4 h = { (_Float16)v.x, (_Float16)v.y, (_Float16)v.z, (_Float16)v.w };
        *(f16x4*)&Xs[r][44 + q * 4] = h;
    }
    for (int idx = tid; idx < 64 * 28; idx += 512) {
        int r = idx / 28, j = idx - r * 28;
        Xs[r][172 + j] = (_Float16)0.f;
    }
}

// one pass: 6 K-chunks x 6 N-tiles per wave (cols half*96 + t*16 + l15)
__device__ __forceinline__ void gemm_pass6(
    const _Float16 (*X)[200], const _Float16* __restrict__ B,
    f32x4* acc, int msub, int half, int l15, int kq, int lane)
{
    #pragma unroll
    for (int t = 0; t < 6; ++t) acc[t] = (f32x4){0.f, 0.f, 0.f, 0.f};
    #pragma unroll
    for (int c = 0; c < 6; ++c) {
        f16x8 a = *(const f16x8*)&X[msub * 16 + l15][c * 32 + kq * 8];
        #pragma unroll
        for (int t = 0; t < 6; ++t) {
            f16x8 b = *(const f16x8*)(B + (((size_t)c * 12 + half * 6 + t) * 64 + lane) * 8);
            acc[t] = MFMA16(a, b, acc[t]);
        }
    }
}

// ---------------- fused tail: dnn1+dnn2+pred1(a,b)+cross+pred2+sigmoid ----
__global__ __launch_bounds__(512, 3) void tail_kernel(
    const int* __restrict__ disc, const float* __restrict__ cont,
    const float* __restrict__ Wc, const float* __restrict__ bc,
    const float* __restrict__ xg,
    const _Float16* __restrict__ W1, const float* __restrict__ b1,
    const _Float16* __restrict__ W2, const float* __restrict__ b2,
    const _Float16* __restrict__ Pa, const _Float16* __restrict__ Pb,
    const float* __restrict__ pb1,
    const float* __restrict__ cw, const float* __restrict__ cvec,
    const float* __restrict__ pw2, const float* __restrict__ pb2,
    float* __restrict__ out, int N)
{
    __shared__ __attribute__((aligned(16))) _Float16 Xs[64][200];
    __shared__ __attribute__((aligned(16))) _Float16 Ts[64][200];
    __shared__ float als[64];
    __shared__ float partial[64][2];
    const int tid = threadIdx.x, lane = tid & 63, wv = tid >> 6;
    const int msub = wv >> 1, half = wv & 1, l15 = lane & 15, kq = lane >> 4;
    const int row0 = blockIdx.x * 64;

    stage_x16(disc, cont, Wc, bc, xg, Xs, row0, N, tid);
    __syncthreads();

    // per-row cross scalars: xl2 = als*x0 + (b1c+b2c)
    {
        int row = tid >> 3, sub = tid & 7;
        float d1 = 0.f, d2 = 0.f;
        for (int col = sub; col < 172; col += 8) {
            float x = (float)Xs[row][col];
            d1 += x * cw[col];
            d2 += x * cw[172 + col];
        }
        #pragma unroll
        for (int off = 1; off < 8; off <<= 1) {
            d1 += __shfl_xor(d1, off, 64);
            d2 += __shfl_xor(d2, off, 64);
        }
        if (sub == 0) {
            float a1 = 1.f + d1;
            als[row] = a1 + a1 * d2 + cvec[176];
        }
    }

    f32x4 accA[6], accB[6];

    // dnn1: Xs -> Ts
    gemm_pass6(Xs, W1, accA, msub, half, l15, kq, lane);
    #pragma unroll
    for (int t = 0; t < 6; ++t) {
        int col = half * 96 + t * 16 + l15;
        #pragma unroll
        for (int r = 0; r < 4; ++r) {
            int row = msub * 16 + kq * 4 + r;
            float v = (col < 172) ? leakyf(accA[t][r] + b1[col]) : 0.f;
            Ts[row][col] = (_Float16)v;
        }
    }
    __syncthreads();
    // dnn2: Ts -> Ts (in place)
    gemm_pass6(Ts, W2, accA, msub, half, l15, kq, lane);
    __syncthreads();
    #pragma unroll
    for (int t = 0; t < 6; ++t) {
        int col = half * 96 + t * 16 + l15;
        #pragma unroll
        for (int r = 0; r < 4; ++r) {
            int row = msub * 16 + kq * 4 + r;
            float v = (col < 172) ? leakyf(accA[t][r] + b2[col]) : 0.f;
            Ts[row][col] = (_Float16)v;
        }
    }
    __syncthreads();

    // pred1: accA = xdeep@Pa (from Ts), accB = x0@Pb (from Xs)
    gemm_pass6(Ts, Pa, accA, msub, half, l15, kq, lane);
    gemm_pass6(Xs, Pb, accB, msub, half, l15, kq, lane);

    // epilogue: pre = accA + pb1 + als*accB + cvec -> leaky -> . pw2 -> sigmoid
    float part[4] = {0.f, 0.f, 0.f, 0.f};
    #pragma unroll
    for (int t = 0; t < 6; ++t) {
        int col = half * 96 + t * 16 + l15;
        if (col < 172) {
            float cv = cvec[col] + pb1[col], w2v = pw2[col];
            #pragma unroll
            for (int r = 0; r < 4; ++r) {
                int row = msub * 16 + kq * 4 + r;
                float pre = accA[t][r] + als[row] * accB[t][r] + cv;
                part[r] += leakyf(pre) * w2v;
            }
        }
    }
    #pragma unroll
    for (int r = 0; r < 4; ++r) {
        #pragma unroll
        for (int off = 1; off < 16; off <<= 1)
            part[r] += __shfl_xor(part[r], off, 64);
    }
    if (l15 == 0) {
        #pragma unroll
        for (int r = 0; r < 4; ++r)
            partial[msub * 16 + kq * 4 + r][half] = part[r];
    }
    __syncthreads();
    if (tid < 64) {
        int grow = row0 + tid;
        if (grow < N) {
            float s = partial[tid][0] + partial[tid][1] + pb2[0];
            out[grow] = 1.f / (1.f + expf(-s));
        }
    }
}

extern "C" void kernel_launch(void* const* d_in, const int* in_sizes, int n_in,
                              void* d_out, int out_size, void* d_ws, size_t ws_size,
                              hipStream_t stream)
{
    const int*   disc    = (const int*)d_in[0];
    const float* cont    = (const float*)d_in[1];
    const int*   eidx    = (const int*)d_in[2];
    const float* emb_W   = (const float*)d_in[5];
    const float* emb_b   = (const float*)d_in[6];
    const float* g0_W    = (const float*)d_in[7];
    const float* g0_b    = (const float*)d_in[8];
    const float* gcn1_W  = (const float*)d_in[9];
    const float* gcn1_b  = (const float*)d_in[10];
    const float* gcn2_W  = (const float*)d_in[11];
    const float* gcn2_b  = (const float*)d_in[12];
    const float* dnn_W1  = (const float*)d_in[13];
    const float* dnn_b1  = (const float*)d_in[14];
    const float* dnn_W2  = (const float*)d_in[15];
    const float* dnn_b2  = (const float*)d_in[16];
    const float* cross_w = (const float*)d_in[17];
    const float* cross_b = (const float*)d_in[18];
    const float* pred_W1 = (const float*)d_in[19];
    const float* pred_b1 = (const float*)d_in[20];
    const float* pred_W2 = (const float*)d_in[21];
    const float* pred_b2 = (const float*)d_in[22];

    const int N = in_sizes[0] / 38;
    const int E = in_sizes[2] / 2;
    const int* src = eidx;
    const int* dst = eidx + E;

    // ---- workspace (~117 MB — round-12 proven layout; Z renamed xgB) ----
    float* xgA  = (float*)d_ws;                       // [N,128] f32
    float* xgB  = xgA + (size_t)128 * N;              // [N,128] f32
    float* dis  = xgB + (size_t)128 * N;              // [N]
    int* cnt    = (int*)(dis + N);                    // [N]
    int* rowp   = cnt + N;                            // [N]
    int* curs   = rowp + N;                           // [N] (incl -> cursor -> end)
    int* bsum   = curs + N;                           // [512]
    int2* colcf = (int2*)(((size_t)(bsum + 512) + 15) & ~(size_t)15);  // [E] {src,coeff}
    _Float16* wf = (_Float16*)(colcf + E);
    _Float16* G1f = wf;              // 4*8*512   = 16384
    _Float16* G2f = G1f + 16384;
    _Float16* W1f = G2f + 16384;     // 6*12*512  = 36864
    _Float16* W2f = W1f + 36864;
    _Float16* Paf = W2f + 36864;
    _Float16* Pbf = Paf + 36864;
    float* cvec   = (float*)(Pbf + 36864);            // [192]

    auto cdiv = [](int a, int b) { return (a + b - 1) / b; };
    const int nb = cdiv(N, 256);

    // weight prep: all planes + cvec in ONE launch
    wprep_kernel<<<705, 256, 0, stream>>>(
        gcn1_W, gcn2_W, dnn_W1, dnn_W2, pred_W1, cross_b, cross_w,
        G1f, G2f, W1f, W2f, Paf, Pbf, cvec);

    // CSR build (+ per-edge coeff); dis folded into scan3
    hipMemsetAsync(cnt, 0, (size_t)N * sizeof(int), stream);
    cnt_edge_kernel<<<cdiv(E, 256), 256, 0, stream>>>(dst, cnt, E);
    scan1_kernel<<<nb, 256, 0, stream>>>(cnt, curs, bsum, N);
    scan2_kernel<<<1, 64, 0, stream>>>(bsum, nb);
    scan3_kernel<<<nb, 256, 0, stream>>>(curs, cnt, bsum, rowp, curs, dis, N);
    fill_kernel<<<cdiv(E, 256), 256, 0, stream>>>(src, dst, dis, curs, colcf, E);

    // g0 -> xgA
    g0_kernel<<<cdiv(N, 32), 256, 0, stream>>>(disc, cont, emb_W, emb_b, g0_W, g0_b, xgA, N);

    // GCN layers (agg fused with GEMM; ping-pong xgA <-> xgB)
    gcn_fused<<<cdiv(N, 64), 512, 0, stream>>>(xgA, colcf, rowp, curs, dis, G1f, gcn1_b, xgB, N);
    gcn_fused<<<cdiv(N, 64), 512, 0, stream>>>(xgB, colcf, rowp, curs, dis, G2f, gcn2_b, xgA, N);

    // fused tail -> out
    tail_kernel<<<cdiv(N, 64), 512, 0, stream>>>(
        disc, cont, emb_W, emb_b, xgA,
        W1f, dnn_b1, W2f, dnn_b2, Paf, Pbf, pred_b1,
        cross_w, cvec, pred_W2, pred_b2, (float*)d_out, N);
}